// Round 7
// baseline (254.253 us; speedup 1.0000x reference)
//
#include <hip/hip_runtime.h>

// LongformerAttention MI355X — Round 6 (Round 5 + host-pass compile fix).
// attn: chained-MFMA transposed flash — S^T via MFMA(A=K,B=Q) leaves P^T in
// C-layout == B-operand layout of mfma_16x16x16_bf16; PV consumes P from
// registers (A = V^T frags). No LDS, no P round-trip. Split-K + maskless fast
// paths + XCD pinning kept. GEMM/cvt/combine unchanged from Round 4.

#define B_   2
#define S_   2048
#define DM   1024
#define H_   16
#define NG   204                     // max(1, int(S*0.1))
#define BS_  4096                    // B_*S_
#define SCL2 0.1803368801111204f     // (1/sqrt(64)) * log2(e)
#define NEGF -3.0e38f

typedef unsigned short u16;
typedef unsigned int   u32;
typedef __attribute__((ext_vector_type(8))) short frag8;   // 8 x bf16
typedef __attribute__((ext_vector_type(4))) short frag4;   // 4 x bf16
typedef __attribute__((ext_vector_type(4))) float f32x4;

#define MFMA16(A, Bf, C) __builtin_amdgcn_mfma_f32_16x16x32_bf16((A), (Bf), (C), 0, 0, 0)

// K=16 bf16 MFMA (v_mfma_f32_16x16x16_bf16, A/B = 4 bf16 each). The builtin is
// visible in the device pass; host pass parses a no-op fallback (host never
// executes device code).
__device__ __forceinline__ f32x4 mfma_16x16x16_bf16(frag4 a, frag4 b, f32x4 c) {
#if defined(__HIP_DEVICE_COMPILE__)
  return __builtin_amdgcn_mfma_f32_16x16x16bf16_1k(a, b, c, 0, 0, 0);
#else
  (void)a; (void)b;
  return c;
#endif
}

#define GLD16(g, l)                                                              \
  __builtin_amdgcn_global_load_lds((const __attribute__((address_space(1))) u32*)(g), \
                                   (__attribute__((address_space(3))) u32*)(l), 16, 0, 0)

#define EXP2(x) exp2f(x)

__device__ __forceinline__ u16 f2bf(float f) {
  union { float f; u32 u; } c; c.f = f;
  u32 u = c.u + 0x7fffu + ((c.u >> 16) & 1u);   // RNE
  return (u16)(u >> 16);
}

// ---------------- fp32 -> bf16 convert, all buffers in one launch ----------------
__global__ void cvt_all(const float* __restrict__ X,  const float* __restrict__ Wq,
                        const float* __restrict__ Wk, const float* __restrict__ Wv,
                        const float* __restrict__ Wo,
                        u16* Xb, u16* Wqb, u16* Wkb, u16* Wvb, u16* Wob) {
  const int chunk = blockIdx.y;
  const float* src; u16* dst;
  if (chunk < 4)      { src = X + (size_t)chunk * 1048576; dst = Xb + (size_t)chunk * 1048576; }
  else if (chunk == 4){ src = Wq; dst = Wqb; }
  else if (chunk == 5){ src = Wk; dst = Wkb; }
  else if (chunk == 6){ src = Wv; dst = Wvb; }
  else                { src = Wo; dst = Wob; }
  int i = blockIdx.x * 256 + threadIdx.x;
  float4 v = ((const float4*)src)[i];
  u32 lo = (u32)f2bf(v.x) | ((u32)f2bf(v.y) << 16);
  u32 hi = (u32)f2bf(v.z) | ((u32)f2bf(v.w) << 16);
  ((uint2*)dst)[i] = make_uint2(lo, hi);
}

// ---------------- m97-style GEMM mainloop, 256 threads, 128x128 tile ----------------
__device__ __forceinline__ void gemm_mainloop(const u16* __restrict__ A, const u16* __restrict__ Bm,
                                              int bm, int bn, u16* As, u16* Bs,
                                              f32x4 acc[4][4]) {
  const int tid = threadIdx.x;
  const int wv = tid >> 6, lane = tid & 63, l15 = lane & 15, quad = lane >> 4;
  const int wm = wv & 1, wn = wv >> 1;

  const u16* gA[4]; const u16* gB[4];
#pragma unroll
  for (int c = 0; c < 4; ++c) {
    int idx = (wv * 4 + c) * 64 + lane;
    int r = idx >> 3;
    int cb = (idx & 7) ^ (r & 7);
    gA[c] = A  + (size_t)(bm + r) * DM + cb * 8;
    gB[c] = Bm + (size_t)(bn + r) * DM + cb * 8;
  }

  int offA[4][2], offB[4][2];
#pragma unroll
  for (int i = 0; i < 4; ++i)
#pragma unroll
    for (int h = 0; h < 2; ++h) {
      int mA = wm * 64 + i * 16 + l15;
      int mB = wn * 64 + i * 16 + l15;
      int cb = (quad + h * 4) ^ (l15 & 7);
      offA[i][h] = ((mA << 3) + cb) << 4;
      offB[i][h] = ((mB << 3) + cb) << 4;
    }

  for (int k0 = 0; k0 < DM; k0 += 64) {
#pragma unroll
    for (int c = 0; c < 4; ++c) {
      GLD16(gA[c] + k0, (char*)As + (wv * 4 + c) * 1024);
      GLD16(gB[c] + k0, (char*)Bs + (wv * 4 + c) * 1024);
    }
    __syncthreads();
    frag8 af[4][2], bf[4][2];
#pragma unroll
    for (int i = 0; i < 4; ++i) {
      af[i][0] = *(const frag8*)((const char*)As + offA[i][0]);
      af[i][1] = *(const frag8*)((const char*)As + offA[i][1]);
      bf[i][0] = *(const frag8*)((const char*)Bs + offB[i][0]);
      bf[i][1] = *(const frag8*)((const char*)Bs + offB[i][1]);
    }
#pragma unroll
    for (int h = 0; h < 2; ++h)
#pragma unroll
      for (int i = 0; i < 4; ++i)
#pragma unroll
        for (int j = 0; j < 4; ++j)
          acc[i][j] = MFMA16(af[i][h], bf[j][h], acc[i][j]);
    __syncthreads();
  }
}

__global__ __launch_bounds__(256, 3) void gemm_qkv(const u16* __restrict__ Xb,
    const u16* __restrict__ Wqb, const u16* __restrict__ Wkb, const u16* __restrict__ Wvb,
    const float* __restrict__ bq, const float* __restrict__ bk, const float* __restrict__ bv,
    u16* __restrict__ Qb, u16* __restrict__ Kb, u16* __restrict__ Vt) {
  __shared__ u16 As[8192], Bs[8192];
  const int bm = blockIdx.y * 128;
  const int which = blockIdx.x >> 3;
  const int bnl = (blockIdx.x & 7) * 128;
  const u16* W = (which == 0) ? Wqb : (which == 1) ? Wkb : Wvb;
  const float* bias = (which == 0) ? bq : (which == 1) ? bk : bv;

  f32x4 acc[4][4] = {};
  gemm_mainloop(Xb, W, bm, bnl, As, Bs, acc);

  const int tid = threadIdx.x, wv = tid >> 6, lane = tid & 63, l15 = lane & 15, quad = lane >> 4;
  const int wm = wv & 1, wn = wv >> 1;
  if (which < 2) {
    u16* O = (which == 0) ? Qb : Kb;
#pragma unroll
    for (int j = 0; j < 4; ++j) {
      int col = bnl + wn * 64 + j * 16 + l15;
      float bb = bias[col];
#pragma unroll
      for (int i = 0; i < 4; ++i) {
        int row0 = bm + wm * 64 + i * 16 + quad * 4;
#pragma unroll
        for (int r = 0; r < 4; ++r)
          O[(size_t)(row0 + r) * DM + col] = f2bf(acc[i][j][r] + bb);
      }
    }
  } else {
#pragma unroll
    for (int j = 0; j < 4; ++j) {
      int col = bnl + wn * 64 + j * 16 + l15;
      float bb = bias[col];
#pragma unroll
      for (int i = 0; i < 4; ++i) {
        int row0 = bm + wm * 64 + i * 16 + quad * 4;
        u32 lo = (u32)f2bf(acc[i][j][0] + bb) | ((u32)f2bf(acc[i][j][1] + bb) << 16);
        u32 hi = (u32)f2bf(acc[i][j][2] + bb) | ((u32)f2bf(acc[i][j][3] + bb) << 16);
        *(uint2*)&Vt[(size_t)col * BS_ + row0] = make_uint2(lo, hi);
      }
    }
  }
}

// ---------------- Wo GEMM: 512 threads (8 waves), 128x128 tile ----------------
__global__ __launch_bounds__(512, 2) void gemm_wo(const u16* __restrict__ Cx,
    const u16* __restrict__ Wob, const float* __restrict__ bo, float* __restrict__ out) {
  __shared__ u16 As[8192], Bs[8192];
  const int bm = blockIdx.y * 128, bn = blockIdx.x * 128;
  const int tid = threadIdx.x;
  const int wv = tid >> 6, lane = tid & 63, l15 = lane & 15, quad = lane >> 4;
  const int wm = wv & 1, wn = wv >> 1;

  const u16* gA[2]; const u16* gB[2];
#pragma unroll
  for (int c = 0; c < 2; ++c) {
    int idx = (wv * 2 + c) * 64 + lane;
    int r = idx >> 3;
    int cb = (idx & 7) ^ (r & 7);
    gA[c] = Cx  + (size_t)(bm + r) * DM + cb * 8;
    gB[c] = Wob + (size_t)(bn + r) * DM + cb * 8;
  }
  int offA[4][2], offB[2][2];
#pragma unroll
  for (int h = 0; h < 2; ++h) {
#pragma unroll
    for (int i = 0; i < 4; ++i) {
      int mA = wm * 64 + i * 16 + l15;
      offA[i][h] = ((mA << 3) + ((quad + h * 4) ^ (l15 & 7))) << 4;
    }
#pragma unroll
    for (int j = 0; j < 2; ++j) {
      int nB = wn * 32 + j * 16 + l15;
      offB[j][h] = ((nB << 3) + ((quad + h * 4) ^ (l15 & 7))) << 4;
    }
  }

  f32x4 acc[4][2] = {};
  for (int k0 = 0; k0 < DM; k0 += 64) {
#pragma unroll
    for (int c = 0; c < 2; ++c) {
      GLD16(gA[c] + k0, (char*)As + (wv * 2 + c) * 1024);
      GLD16(gB[c] + k0, (char*)Bs + (wv * 2 + c) * 1024);
    }
    __syncthreads();
    frag8 af[4][2], bf[2][2];
#pragma unroll
    for (int i = 0; i < 4; ++i) {
      af[i][0] = *(const frag8*)((const char*)As + offA[i][0]);
      af[i][1] = *(const frag8*)((const char*)As + offA[i][1]);
    }
#pragma unroll
    for (int j = 0; j < 2; ++j) {
      bf[j][0] = *(const frag8*)((const char*)Bs + offB[j][0]);
      bf[j][1] = *(const frag8*)((const char*)Bs + offB[j][1]);
    }
#pragma unroll
    for (int h = 0; h < 2; ++h)
#pragma unroll
      for (int i = 0; i < 4; ++i)
#pragma unroll
        for (int j = 0; j < 2; ++j)
          acc[i][j] = MFMA16(af[i][h], bf[j][h], acc[i][j]);
    __syncthreads();
  }

#pragma unroll
  for (int j = 0; j < 2; ++j) {
    int col = bn + wn * 32 + j * 16 + l15;
    float bb = bo[col];
#pragma unroll
    for (int i = 0; i < 4; ++i) {
      int row0 = bm + wm * 64 + i * 16 + quad * 4;
#pragma unroll
      for (int r = 0; r < 4; ++r)
        out[(size_t)(row0 + r) * DM + col] = acc[i][j][r] + bb;
    }
  }
}

// ---------------- Flash attention: chained-MFMA transposed, no LDS ----------------
// Units per bh: 28 split (strips 0..6 x 4 segs of 8 tiles) + 57 window
// (strips 7..63). Grid 85*32; bh = blk&31 (XCD-pinned), unit = blk>>5.
// Per wave: S^T[key][q] = MFMA(A=K, B=Q) -> C-layout (lane: q=l15, keys=quad*4+r)
// == B-operand layout of mfma_16x16x16; PV: O^T += MFMA(A=V^T, B=P^T).
__global__ __launch_bounds__(128, 2) void attn_kernel(const u16* __restrict__ Q,
                                                      const u16* __restrict__ K,
                                                      const u16* __restrict__ Vt,
                                                      u16* __restrict__ Ctx,
                                                      float* __restrict__ Op,
                                                      float* __restrict__ Lp) {
  const int tid = threadIdx.x, w = tid >> 6, lane = tid & 63, l15 = lane & 15, quad = lane >> 4;
  const int blk = blockIdx.x;
  const int bh = blk & 31, unit = blk >> 5;
  const int b = bh >> 4, h = bh & 15;
  const bool split = unit < 28;
  const int strip = split ? (unit >> 2) : (unit - 21);
  const int q0 = strip * 32;
  const int qw = q0 + w * 16;

  // Q B-frags (n = q = l15, k = d = quad*8+j)
  const u16* qrow = Q + (size_t)(b * S_ + qw + l15) * DM + h * 64;
  frag8 aq0 = *(const frag8*)(qrow + quad * 8);
  frag8 aq1 = *(const frag8*)(qrow + quad * 8 + 32);

  // K A-frag base (m = key = l15, k = d = quad*8+j)
  const u16* kb = K + (size_t)((size_t)b * S_ + l15) * DM + h * 64 + quad * 8;
  // V^T A-frag base (m = d = l15 per 16-group, k = key = quad*4+j)
  const u16* vb2 = Vt + (size_t)((size_t)h * 64 + l15) * BS_ + (size_t)b * S_ + quad * 4;

  const int qidx = qw + l15;
  const bool qglob = qidx < NG;

  f32x4 o[4] = {};        // O^T C-frags: row d = nt*16+quad*4+r, col q = l15
  float lsum = 0.f;       // per-lane (q = l15), reduced across quads at end

  auto loadK = [&](int t, frag8* d0, frag8* d1) {
    const u16* kp = kb + (size_t)(t * 64) * DM;
#pragma unroll
    for (int kg = 0; kg < 4; ++kg) {
      d0[kg] = *(const frag8*)(kp + (size_t)(kg * 16) * DM);
      d1[kg] = *(const frag8*)(kp + (size_t)(kg * 16) * DM + 32);
    }
  };

  frag8 Ak0[4], Ak1[4];
  frag8 Bk0[4], Bk1[4];

  auto step = [&](int cur, int nxt, bool more, frag8* k0f, frag8* k1f,
                  frag8* nk0, frag8* nk1, bool domask) {
    const int k0 = cur * 64;
    // V^T A-frags for CURRENT tile — issued first, consumed after softmax
    frag4 av[4][4];
    const u16* vp = vb2 + k0;
#pragma unroll
    for (int nt = 0; nt < 4; ++nt)
#pragma unroll
      for (int kg = 0; kg < 4; ++kg)
        av[nt][kg] = *(const frag4*)(vp + (size_t)(nt * 16) * BS_ + kg * 16);

    // S^T = K_tile (64key x 64d) . Q^T -> 4 C-frags (16 keys each)
    f32x4 st[4] = {};
#pragma unroll
    for (int kg = 0; kg < 4; ++kg) {
      st[kg] = MFMA16(k0f[kg], aq0, st[kg]);
      st[kg] = MFMA16(k1f[kg], aq1, st[kg]);
    }
    if (more) loadK(nxt, nk0, nk1);        // K prefetch overlaps softmax+PV

    frag4 pk[4];
    if (domask) {
#pragma unroll
      for (int kg = 0; kg < 4; ++kg) {
        float pr[4];
#pragma unroll
        for (int r = 0; r < 4; ++r) {
          int kc = k0 + kg * 16 + quad * 4 + r;
          int d = qidx - kc;
          bool act = ((unsigned)(d + 64) <= 128u) || qglob || (kc < NG);
          float p = EXP2(act ? st[kg][r] * SCL2 : NEGF);
          pr[r] = p; lsum += p;
        }
        pk[kg] = frag4{(short)f2bf(pr[0]), (short)f2bf(pr[1]),
                       (short)f2bf(pr[2]), (short)f2bf(pr[3])};
      }
    } else {
#pragma unroll
      for (int kg = 0; kg < 4; ++kg) {
        float pr[4];
#pragma unroll
        for (int r = 0; r < 4; ++r) {
          float p = EXP2(st[kg][r] * SCL2);
          pr[r] = p; lsum += p;
        }
        pk[kg] = frag4{(short)f2bf(pr[0]), (short)f2bf(pr[1]),
                       (short)f2bf(pr[2]), (short)f2bf(pr[3])};
      }
    }

    // O^T += V^T(64d x 64key) . P^T — P straight from registers
#pragma unroll
    for (int nt = 0; nt < 4; ++nt)
#pragma unroll
      for (int kg = 0; kg < 4; ++kg)
        o[nt] = mfma_16x16x16_bf16(av[nt][kg], pk[kg], o[nt]);
  };

  if (split) {
    const int seg = unit & 3;
    const int kt0 = seg * 8;
    const bool dm = (strip == 6);          // rows 192..223 straddle NG cutoff

    loadK(kt0, Ak0, Ak1);
#pragma unroll
    for (int tt = 0; tt < 8; tt += 2) {
      int t0 = kt0 + tt, t1 = kt0 + tt + 1;
      step(t0, t1, true, Ak0, Ak1, Bk0, Bk1, dm && (t0 > 2));
      step(t1, t1 + 1, tt + 2 < 8, Bk0, Bk1, Ak0, Ak1, dm && (t1 > 2));
    }

    lsum += __shfl_xor(lsum, 16);
    lsum += __shfl_xor(lsum, 32);

    float* op = Op + ((size_t)((bh * 7 + strip) * 4 + seg)) * 2048;  // [32 rows][64 d]
    float* lp = Lp + ((size_t)((bh * 7 + strip) * 4 + seg)) * 32;
    if (quad == 0) lp[w * 16 + l15] = lsum;
#pragma unroll
    for (int nt = 0; nt < 4; ++nt)
      *(float4*)&op[(w * 16 + l15) * 64 + nt * 16 + quad * 4] =
          make_float4(o[nt][0], o[nt][1], o[nt][2], o[nt][3]);
    return;
  }

  // ---- window path (strips 7..63): tiles 0..2 maskless (all-global cols) ----
  auto activef = [&](int t) {
    int k0 = t * 64;
    return (k0 < NG) || (k0 + 63 >= q0 - 64 && k0 <= q0 + 95);
  };
  auto nextt = [&](int cur) { int n = cur + 1; while (n < 32 && !activef(n)) ++n; return n; };

  int kt = 0;                              // tile 0 always active (global cols)
  loadK(0, Ak0, Ak1);
  for (;;) {
    int ktn = nextt(kt);
    bool more = ktn < 32;
    step(kt, ktn, more, Ak0, Ak1, Bk0, Bk1, kt > 2);
    if (!more) break;
    kt = ktn;
    ktn = nextt(kt);
    more = ktn < 32;
    step(kt, ktn, more, Bk0, Bk1, Ak0, Ak1, kt > 2);
    if (!more) break;
    kt = ktn;
  }

  lsum += __shfl_xor(lsum, 16);
  lsum += __shfl_xor(lsum, 32);
  float inv = 1.0f / lsum;

  u16* crow = Ctx + (size_t)((size_t)b * S_ + qw + l15) * DM + h * 64;
#pragma unroll
  for (int nt = 0; nt < 4; ++nt) {
    u32 lo = (u32)f2bf(o[nt][0] * inv) | ((u32)f2bf(o[nt][1] * inv) << 16);
    u32 hi = (u32)f2bf(o[nt][2] * inv) | ((u32)f2bf(o[nt][3] * inv) << 16);
    *(uint2*)&crow[nt * 16 + quad * 4] = make_uint2(lo, hi);
  }
}

// ---------------- combine split-K partials -> Ctx rows 0..223 ----------------
__global__ __launch_bounds__(256) void combine_kernel(const float* __restrict__ Op,
                                                      const float* __restrict__ Lp,
                                                      u16* __restrict__ Ctx) {
  const int blk = blockIdx.x;
  const int bh = blk & 31, strip = blk >> 5;
  const int b = bh >> 4, h = bh & 15;
  const int t = threadIdx.x;
  const int row = t >> 3, colg = (t & 7) * 8;

  const float* opb = Op + ((size_t)(bh * 7 + strip) * 4) * 2048;
  const float* lpb = Lp + ((size_t)(bh * 7 + strip) * 4) * 32;

  float l = lpb[row] + lpb[32 + row] + lpb[64 + row] + lpb[96 + row];
  float acc[8];
#pragma unroll
  for (int e = 0; e < 8; ++e) acc[e] = opb[row * 64 + colg + e];
#pragma unroll
  for (int seg = 1; seg < 4; ++seg)
#pragma unroll
    for (int e = 0; e < 8; ++e) acc[e] += opb[seg * 2048 + row * 64 + colg + e];

  float inv = 1.0f / l;
  u32 pk[4];
#pragma unroll
  for (int p = 0; p < 4; ++p)
    pk[p] = (u32)f2bf(acc[2 * p] * inv) | ((u32)f2bf(acc[2 * p + 1] * inv) << 16);
  uint4 vout = make_uint4(pk[0], pk[1], pk[2], pk[3]);
  *(uint4*)&Ctx[(size_t)((size_t)b * S_ + strip * 32 + row) * DM + h * 64 + colg] = vout;
}

// ---------------- launch ----------------
extern "C" void kernel_launch(void* const* d_in, const int* in_sizes, int n_in,
                              void* d_out, int out_size, void* d_ws, size_t ws_size,
                              hipStream_t stream) {
  const float* X  = (const float*)d_in[0];
  const float* Wq = (const float*)d_in[1];
  const float* bq = (const float*)d_in[2];
  const float* Wk = (const float*)d_in[3];
  const float* bk = (const float*)d_in[4];
  const float* Wv = (const float*)d_in[5];
  const float* bv = (const float*)d_in[6];
  const float* Wo = (const float*)d_in[7];
  const float* bo = (const float*)d_in[8];
  float* out = (float*)d_out;

  u16* ws = (u16*)d_ws;
  const size_t NX = (size_t)BS_ * DM;
  const size_t NW = (size_t)DM * DM;
  u16* Xb  = ws;
  u16* Wqb = Xb + NX;
  u16* Wkb = Wqb + NW;
  u16* Wvb = Wkb + NW;
  u16* Wob = Wvb + NW;
  u16* Qb  = Wob + NW;
  u16* Kb  = Qb + NX;
  u16* Vt  = Kb + NX;
  u16* Cx  = Vt + NX;
  float* Op = (float*)(Cx + NX);
  float* Lp = Op + (size_t)32 * 7 * 4 * 2048;

  cvt_all<<<dim3(1024, 8), 256, 0, stream>>>(X, Wq, Wk, Wv, Wo, Xb, Wqb, Wkb, Wvb, Wob);
  gemm_qkv<<<dim3(24, 32), 256, 0, stream>>>(Xb, Wqb, Wkb, Wvb, bq, bk, bv, Qb, Kb, Vt);
  attn_kernel<<<85 * 32, 128, 0, stream>>>(Qb, Kb, Vt, Cx, Op, Lp);
  combine_kernel<<<224, 256, 0, stream>>>(Op, Lp, Cx);
  gemm_wo<<<dim3(8, 32), 512, 0, stream>>>(Cx, Wob, bo, out);
}

// Round 8
// 185.104 us; speedup vs baseline: 1.3736x; 1.3736x over previous
//
#include <hip/hip_runtime.h>

// LongformerAttention MI355X — Round 7.
// attn: block-cooperative LDS-staged flash (GLD16 async staging, XOR swizzle,
// double-buffered, 4 waves share K/V tiles of one (b,h)) — attacks the
// scattered-VMEM address-generation bottleneck identified in R2-R6.
// gemm_wo: 64x128 tiles, 512 blocks (2/CU). cvt/gemm_qkv unchanged.

#define B_   2
#define S_   2048
#define DM   1024
#define H_   16
#define NG   204                     // max(1, int(S*0.1))
#define BS_  4096                    // B_*S_
#define SCL2 0.1803368801111204f     // (1/sqrt(64)) * log2(e)
#define NEGF -3.0e38f

typedef unsigned short u16;
typedef unsigned int   u32;
typedef __attribute__((ext_vector_type(8))) short frag8;   // 8 x bf16
typedef __attribute__((ext_vector_type(4))) float f32x4;

#define MFMA16(A, Bf, C) __builtin_amdgcn_mfma_f32_16x16x32_bf16((A), (Bf), (C), 0, 0, 0)
#define GLD16(g, l)                                                              \
  __builtin_amdgcn_global_load_lds((const __attribute__((address_space(1))) u32*)(g), \
                                   (__attribute__((address_space(3))) u32*)(l), 16, 0, 0)
#define EXP2(x) exp2f(x)

__device__ __forceinline__ u16 f2bf(float f) {
  union { float f; u32 u; } c; c.f = f;
  u32 u = c.u + 0x7fffu + ((c.u >> 16) & 1u);   // RNE
  return (u16)(u >> 16);
}

// ---------------- fp32 -> bf16 convert, all buffers in one launch ----------------
__global__ void cvt_all(const float* __restrict__ X,  const float* __restrict__ Wq,
                        const float* __restrict__ Wk, const float* __restrict__ Wv,
                        const float* __restrict__ Wo,
                        u16* Xb, u16* Wqb, u16* Wkb, u16* Wvb, u16* Wob) {
  const int chunk = blockIdx.y;
  const float* src; u16* dst;
  if (chunk < 4)      { src = X + (size_t)chunk * 1048576; dst = Xb + (size_t)chunk * 1048576; }
  else if (chunk == 4){ src = Wq; dst = Wqb; }
  else if (chunk == 5){ src = Wk; dst = Wkb; }
  else if (chunk == 6){ src = Wv; dst = Wvb; }
  else                { src = Wo; dst = Wob; }
  int i = blockIdx.x * 256 + threadIdx.x;
  float4 v = ((const float4*)src)[i];
  u32 lo = (u32)f2bf(v.x) | ((u32)f2bf(v.y) << 16);
  u32 hi = (u32)f2bf(v.z) | ((u32)f2bf(v.w) << 16);
  ((uint2*)dst)[i] = make_uint2(lo, hi);
}

// ---------------- m97-style GEMM mainloop, 256 threads, 128x128 tile ----------------
__device__ __forceinline__ void gemm_mainloop(const u16* __restrict__ A, const u16* __restrict__ Bm,
                                              int bm, int bn, u16* As, u16* Bs,
                                              f32x4 acc[4][4]) {
  const int tid = threadIdx.x;
  const int wv = tid >> 6, lane = tid & 63, l15 = lane & 15, quad = lane >> 4;
  const int wm = wv & 1, wn = wv >> 1;

  const u16* gA[4]; const u16* gB[4];
#pragma unroll
  for (int c = 0; c < 4; ++c) {
    int idx = (wv * 4 + c) * 64 + lane;
    int r = idx >> 3;
    int cb = (idx & 7) ^ (r & 7);
    gA[c] = A  + (size_t)(bm + r) * DM + cb * 8;
    gB[c] = Bm + (size_t)(bn + r) * DM + cb * 8;
  }

  int offA[4][2], offB[4][2];
#pragma unroll
  for (int i = 0; i < 4; ++i)
#pragma unroll
    for (int h = 0; h < 2; ++h) {
      int mA = wm * 64 + i * 16 + l15;
      int mB = wn * 64 + i * 16 + l15;
      int cb = (quad + h * 4) ^ (l15 & 7);
      offA[i][h] = ((mA << 3) + cb) << 4;
      offB[i][h] = ((mB << 3) + cb) << 4;
    }

  for (int k0 = 0; k0 < DM; k0 += 64) {
#pragma unroll
    for (int c = 0; c < 4; ++c) {
      GLD16(gA[c] + k0, (char*)As + (wv * 4 + c) * 1024);
      GLD16(gB[c] + k0, (char*)Bs + (wv * 4 + c) * 1024);
    }
    __syncthreads();
    frag8 af[4][2], bf[4][2];
#pragma unroll
    for (int i = 0; i < 4; ++i) {
      af[i][0] = *(const frag8*)((const char*)As + offA[i][0]);
      af[i][1] = *(const frag8*)((const char*)As + offA[i][1]);
      bf[i][0] = *(const frag8*)((const char*)Bs + offB[i][0]);
      bf[i][1] = *(const frag8*)((const char*)Bs + offB[i][1]);
    }
#pragma unroll
    for (int h = 0; h < 2; ++h)
#pragma unroll
      for (int i = 0; i < 4; ++i)
#pragma unroll
        for (int j = 0; j < 4; ++j)
          acc[i][j] = MFMA16(af[i][h], bf[j][h], acc[i][j]);
    __syncthreads();
  }
}

__global__ __launch_bounds__(256, 3) void gemm_qkv(const u16* __restrict__ Xb,
    const u16* __restrict__ Wqb, const u16* __restrict__ Wkb, const u16* __restrict__ Wvb,
    const float* __restrict__ bq, const float* __restrict__ bk, const float* __restrict__ bv,
    u16* __restrict__ Qb, u16* __restrict__ Kb, u16* __restrict__ Vt) {
  __shared__ u16 As[8192], Bs[8192];
  const int bm = blockIdx.y * 128;
  const int which = blockIdx.x >> 3;
  const int bnl = (blockIdx.x & 7) * 128;
  const u16* W = (which == 0) ? Wqb : (which == 1) ? Wkb : Wvb;
  const float* bias = (which == 0) ? bq : (which == 1) ? bk : bv;

  f32x4 acc[4][4] = {};
  gemm_mainloop(Xb, W, bm, bnl, As, Bs, acc);

  const int tid = threadIdx.x, wv = tid >> 6, lane = tid & 63, l15 = lane & 15, quad = lane >> 4;
  const int wm = wv & 1, wn = wv >> 1;
  if (which < 2) {
    u16* O = (which == 0) ? Qb : Kb;
#pragma unroll
    for (int j = 0; j < 4; ++j) {
      int col = bnl + wn * 64 + j * 16 + l15;
      float bb = bias[col];
#pragma unroll
      for (int i = 0; i < 4; ++i) {
        int row0 = bm + wm * 64 + i * 16 + quad * 4;
#pragma unroll
        for (int r = 0; r < 4; ++r)
          O[(size_t)(row0 + r) * DM + col] = f2bf(acc[i][j][r] + bb);
      }
    }
  } else {
#pragma unroll
    for (int j = 0; j < 4; ++j) {
      int col = bnl + wn * 64 + j * 16 + l15;
      float bb = bias[col];
#pragma unroll
      for (int i = 0; i < 4; ++i) {
        int row0 = bm + wm * 64 + i * 16 + quad * 4;
        u32 lo = (u32)f2bf(acc[i][j][0] + bb) | ((u32)f2bf(acc[i][j][1] + bb) << 16);
        u32 hi = (u32)f2bf(acc[i][j][2] + bb) | ((u32)f2bf(acc[i][j][3] + bb) << 16);
        *(uint2*)&Vt[(size_t)col * BS_ + row0] = make_uint2(lo, hi);
      }
    }
  }
}

// ---------------- Wo GEMM: 64x128 tile, 512 blocks (2/CU), 256 threads ----------------
__global__ __launch_bounds__(256, 3) void gemm_wo(const u16* __restrict__ Cx,
    const u16* __restrict__ Wob, const float* __restrict__ bo, float* __restrict__ out) {
  __shared__ u16 As[4096], Bs[8192];   // A 64x64, B 128x64 (swizzled)
  const int tid = threadIdx.x;
  const int wv = tid >> 6, lane = tid & 63, l15 = lane & 15, quad = lane >> 4;
  const int bm = blockIdx.y * 64, bn = blockIdx.x * 128;

  const u16* gA[2]; const u16* gB[4];
  int ldsA[2], ldsB[4];
#pragma unroll
  for (int c = 0; c < 2; ++c) {
    int slot = c * 256 + wv * 64 + lane;
    int r = slot >> 3, cb = (slot & 7) ^ (r & 7);
    gA[c] = Cx + (size_t)(bm + r) * DM + cb * 8;
    ldsA[c] = (c * 256 + wv * 64) * 16;
  }
#pragma unroll
  for (int c = 0; c < 4; ++c) {
    int slot = c * 256 + wv * 64 + lane;
    int r = slot >> 3, cb = (slot & 7) ^ (r & 7);
    gB[c] = Wob + (size_t)(bn + r) * DM + cb * 8;
    ldsB[c] = (c * 256 + wv * 64) * 16;
  }

  int offA[2], offB[8][2];
#pragma unroll
  for (int h = 0; h < 2; ++h) {
    int rowA = wv * 16 + l15;
    offA[h] = ((rowA << 3) + ((quad + h * 4) ^ (l15 & 7))) << 4;
#pragma unroll
    for (int j = 0; j < 8; ++j) {
      int rowB = j * 16 + l15;
      offB[j][h] = ((rowB << 3) + ((quad + h * 4) ^ (l15 & 7))) << 4;
    }
  }

  f32x4 acc[8] = {};
  for (int k0 = 0; k0 < DM; k0 += 64) {
#pragma unroll
    for (int c = 0; c < 2; ++c) GLD16(gA[c] + k0, (char*)As + ldsA[c]);
#pragma unroll
    for (int c = 0; c < 4; ++c) GLD16(gB[c] + k0, (char*)Bs + ldsB[c]);
    __syncthreads();
    frag8 af0 = *(const frag8*)((const char*)As + offA[0]);
    frag8 af1 = *(const frag8*)((const char*)As + offA[1]);
#pragma unroll
    for (int j = 0; j < 8; ++j) {
      frag8 bf0 = *(const frag8*)((const char*)Bs + offB[j][0]);
      frag8 bf1 = *(const frag8*)((const char*)Bs + offB[j][1]);
      acc[j] = MFMA16(af0, bf0, acc[j]);
      acc[j] = MFMA16(af1, bf1, acc[j]);
    }
    __syncthreads();
  }

#pragma unroll
  for (int j = 0; j < 8; ++j) {
    int col = bn + j * 16 + l15;
    float bb = bo[col];
    int row0 = bm + wv * 16 + quad * 4;
#pragma unroll
    for (int r = 0; r < 4; ++r)
      out[(size_t)(row0 + r) * DM + col] = acc[j][r] + bb;
  }
}

// ---------------- Flash attention: block-cooperative LDS-staged ----------------
// 1024 blocks (32 strips x 32 bh, XCD-pinned, heavy strips first), 256 thr =
// 4 waves x 16 q-rows. K tile [key][d] and V^T tile [d][key] (8 KB each,
// XOR-swizzled 16B blocks) staged via GLD16, double-buffered; 1 barrier/step.
__global__ __launch_bounds__(256) void attn_kernel(const u16* __restrict__ Q,
                                                   const u16* __restrict__ K,
                                                   const u16* __restrict__ Vt,
                                                   u16* __restrict__ Ctx) {
  __shared__ u16 Ks[2][4096];     // [buf][64 rows x 64 d] swizzled
  __shared__ u16 Vs[2][4096];     // [buf][64 d x 64 keys] swizzled
  __shared__ u16 Ps[4][16 * 76];  // per-wave P transpose

  const int tid = threadIdx.x, w = tid >> 6, lane = tid & 63, l15 = lane & 15, quad = lane >> 4;
  const int blk = blockIdx.x;
  const int xcd = blk & 7, slot = blk >> 3;
  const int bh = xcd + 8 * (slot & 3);
  const int strip = slot >> 2;             // 0..31, heavy (0..3) dispatch first
  const int b = bh >> 4, h = bh & 15;
  const int q0 = strip * 64;
  const int qw = q0 + w * 16;

  // Q A-frags (m = q = l15, k = d = quad*8+j)
  const u16* qrow = Q + (size_t)(b * S_ + qw + l15) * DM + h * 64;
  frag8 aq0 = *(const frag8*)(qrow + quad * 8);
  frag8 aq1 = *(const frag8*)(qrow + quad * 8 + 32);

  // staging pointers (2 GLD16 per matrix per wave)
  const u16* gK[2]; const u16* gV[2]; int ldso[2];
#pragma unroll
  for (int c = 0; c < 2; ++c) {
    int sl = (w * 2 + c) * 64 + lane;
    int r = sl >> 3, cb = (sl & 7) ^ (r & 7);
    gK[c] = K  + (size_t)(b * S_ + r) * DM + h * 64 + cb * 8;       // + kt*64*DM
    gV[c] = Vt + (size_t)(h * 64 + r) * BS_ + (size_t)b * S_ + cb * 8;  // + kt*64
    ldso[c] = (w * 2 + c) * 1024;
  }

  // fragment LDS byte offsets (row g*16+l15, half h) — shared by K and V tiles
  int offF[4][2];
#pragma unroll
  for (int g = 0; g < 4; ++g)
#pragma unroll
    for (int hh = 0; hh < 2; ++hh)
      offF[g][hh] = (((g * 16 + l15) << 3) + ((quad + hh * 4) ^ (l15 & 7))) << 4;

  int qidx[4]; bool qglob[4];
#pragma unroll
  for (int r = 0; r < 4; ++r) { qidx[r] = qw + quad * 4 + r; qglob[r] = qidx[r] < NG; }

  f32x4 o[4] = {};
  float lsum[4] = {0.f, 0.f, 0.f, 0.f};

  auto activef = [&](int t) {
    int k0 = t * 64;
    return (q0 < NG) || (k0 < NG) || (k0 + 63 >= q0 - 64 && k0 <= q0 + 127);
  };
  auto nextt = [&](int cur) { int n = cur + 1; while (n < 32 && !activef(n)) ++n; return n; };
  auto stage = [&](int t, int buf) {
#pragma unroll
    for (int c = 0; c < 2; ++c) {
      GLD16(gK[c] + (size_t)t * 64 * DM, (char*)Ks[buf] + ldso[c]);
      GLD16(gV[c] + t * 64,              (char*)Vs[buf] + ldso[c]);
    }
  };

  int kt = 0, p = 0;                        // tile 0 always active (global cols)
  stage(0, 0);
  for (;;) {
    int ktn = nextt(kt);
    bool more = ktn < 32;
    __syncthreads();                        // buf[p] ready; buf[p^1] free
    if (more) stage(ktn, p ^ 1);

    const char* kb_ = (const char*)Ks[p];
    const char* vb_ = (const char*)Vs[p];

    // S = Q(16x64) . K_tile^T -> 4 C-frags (row q = quad*4+r, col key = l15)
    f32x4 sc[4] = {};
#pragma unroll
    for (int kg = 0; kg < 4; ++kg) {
      frag8 bk0 = *(const frag8*)(kb_ + offF[kg][0]);
      frag8 bk1 = *(const frag8*)(kb_ + offF[kg][1]);
      sc[kg] = MFMA16(aq0, bk0, sc[kg]);
      sc[kg] = MFMA16(aq1, bk1, sc[kg]);
    }
    // V^T B-frags (n = d = nt*16+l15, k = key = quad*8+j)
    frag8 bvf[4][2];
#pragma unroll
    for (int nt = 0; nt < 4; ++nt) {
      bvf[nt][0] = *(const frag8*)(vb_ + offF[nt][0]);
      bvf[nt][1] = *(const frag8*)(vb_ + offF[nt][1]);
    }

    const int k0 = kt * 64;
    const bool domask = (strip > 2) && (kt > 2);   // global rows/cols need no mask
    float pr[4][4];
    if (domask) {
#pragma unroll
      for (int kg = 0; kg < 4; ++kg) {
        int kc = k0 + kg * 16 + l15;
        bool kglob = kc < NG;
#pragma unroll
        for (int r = 0; r < 4; ++r) {
          int d = qidx[r] - kc;
          bool act = ((unsigned)(d + 64) <= 128u) || qglob[r] || kglob;
          float pv = EXP2(act ? sc[kg][r] * SCL2 : NEGF);
          pr[kg][r] = pv; lsum[r] += pv;
        }
      }
    } else {
#pragma unroll
      for (int kg = 0; kg < 4; ++kg)
#pragma unroll
        for (int r = 0; r < 4; ++r) {
          float pv = EXP2(sc[kg][r] * SCL2);
          pr[kg][r] = pv; lsum[r] += pv;
        }
    }

    // P: C-layout -> wave-private LDS -> A-frags
#pragma unroll
    for (int kg = 0; kg < 4; ++kg)
#pragma unroll
      for (int r = 0; r < 4; ++r)
        Ps[w][(quad * 4 + r) * 76 + kg * 16 + l15] = f2bf(pr[kg][r]);
    __asm__ volatile("s_waitcnt lgkmcnt(0)" ::: "memory");
    frag8 ap0 = *(const frag8*)&Ps[w][l15 * 76 + quad * 8];
    frag8 ap1 = *(const frag8*)&Ps[w][l15 * 76 + quad * 8 + 32];

#pragma unroll
    for (int nt = 0; nt < 4; ++nt) {
      o[nt] = MFMA16(ap0, bvf[nt][0], o[nt]);
      o[nt] = MFMA16(ap1, bvf[nt][1], o[nt]);
    }

    if (!more) break;
    kt = ktn; p ^= 1;
  }

#pragma unroll
  for (int off = 8; off; off >>= 1)
#pragma unroll
    for (int r = 0; r < 4; ++r) lsum[r] += __shfl_xor(lsum[r], off);

#pragma unroll
  for (int r = 0; r < 4; ++r) {
    float inv = 1.0f / lsum[r];
    int row = qw + quad * 4 + r;
    u16* crow = Ctx + (size_t)((size_t)b * S_ + row) * DM + h * 64;
#pragma unroll
    for (int nt = 0; nt < 4; ++nt)
      crow[nt * 16 + l15] = f2bf(o[nt][r] * inv);
  }
}

// ---------------- launch ----------------
extern "C" void kernel_launch(void* const* d_in, const int* in_sizes, int n_in,
                              void* d_out, int out_size, void* d_ws, size_t ws_size,
                              hipStream_t stream) {
  const float* X  = (const float*)d_in[0];
  const float* Wq = (const float*)d_in[1];
  const float* bq = (const float*)d_in[2];
  const float* Wk = (const float*)d_in[3];
  const float* bk = (const float*)d_in[4];
  const float* Wv = (const float*)d_in[5];
  const float* bv = (const float*)d_in[6];
  const float* Wo = (const float*)d_in[7];
  const float* bo = (const float*)d_in[8];
  float* out = (float*)d_out;

  u16* ws = (u16*)d_ws;
  const size_t NX = (size_t)BS_ * DM;
  const size_t NW = (size_t)DM * DM;
  u16* Xb  = ws;
  u16* Wqb = Xb + NX;
  u16* Wkb = Wqb + NW;
  u16* Wvb = Wkb + NW;
  u16* Wob = Wvb + NW;
  u16* Qb  = Wob + NW;
  u16* Kb  = Qb + NX;
  u16* Vt  = Kb + NX;
  u16* Cx  = Vt + NX;

  cvt_all<<<dim3(1024, 8), 256, 0, stream>>>(X, Wq, Wk, Wv, Wo, Xb, Wqb, Wkb, Wvb, Wob);
  gemm_qkv<<<dim3(24, 32), 256, 0, stream>>>(Xb, Wqb, Wkb, Wvb, bq, bk, bv, Qb, Kb, Vt);
  attn_kernel<<<1024, 256, 0, stream>>>(Qb, Kb, Vt, Cx);
  gemm_wo<<<dim3(8, 64), 256, 0, stream>>>(Cx, Wob, bo, out);
}

// Round 9
// 179.889 us; speedup vs baseline: 1.4134x; 1.0290x over previous
//
#include <hip/hip_runtime.h>

// LongformerAttention MI355X — Round 8.
// attn = R7 cooperative LDS staging (GLD16, XOR swizzle, double-buffer)
//      + R6 chained-MFMA math (S^T -> P^T in registers -> PV via 16x16x16),
//        deleting the P LDS round-trip; 32 KB LDS -> 4 blocks/CU, no tail.
// cvt/gemm_qkv/gemm_wo unchanged from Round 7.

#define B_   2
#define S_   2048
#define DM   1024
#define H_   16
#define NG   204                     // max(1, int(S*0.1))
#define BS_  4096                    // B_*S_
#define SCL2 0.1803368801111204f     // (1/sqrt(64)) * log2(e)
#define NEGF -3.0e38f

typedef unsigned short u16;
typedef unsigned int   u32;
typedef __attribute__((ext_vector_type(8))) short frag8;   // 8 x bf16
typedef __attribute__((ext_vector_type(4))) short frag4;   // 4 x bf16
typedef __attribute__((ext_vector_type(4))) float f32x4;

#define MFMA16(A, Bf, C) __builtin_amdgcn_mfma_f32_16x16x32_bf16((A), (Bf), (C), 0, 0, 0)

__device__ __forceinline__ f32x4 mfma_16x16x16_bf16(frag4 a, frag4 b, f32x4 c) {
#if defined(__HIP_DEVICE_COMPILE__)
  return __builtin_amdgcn_mfma_f32_16x16x16bf16_1k(a, b, c, 0, 0, 0);
#else
  (void)a; (void)b;
  return c;
#endif
}

#define GLD16(g, l)                                                              \
  __builtin_amdgcn_global_load_lds((const __attribute__((address_space(1))) u32*)(g), \
                                   (__attribute__((address_space(3))) u32*)(l), 16, 0, 0)
#define EXP2(x) exp2f(x)

__device__ __forceinline__ u16 f2bf(float f) {          // RNE (epilogues/GEMM)
  union { float f; u32 u; } c; c.f = f;
  u32 u = c.u + 0x7fffu + ((c.u >> 16) & 1u);
  return (u16)(u >> 16);
}
__device__ __forceinline__ u16 f2bfc(float f) {         // cheap RN (P inner loop)
  union { float f; u32 u; } c; c.f = f;
  return (u16)((c.u + 0x8000u) >> 16);
}

// ---------------- fp32 -> bf16 convert, all buffers in one launch ----------------
__global__ void cvt_all(const float* __restrict__ X,  const float* __restrict__ Wq,
                        const float* __restrict__ Wk, const float* __restrict__ Wv,
                        const float* __restrict__ Wo,
                        u16* Xb, u16* Wqb, u16* Wkb, u16* Wvb, u16* Wob) {
  const int chunk = blockIdx.y;
  const float* src; u16* dst;
  if (chunk < 4)      { src = X + (size_t)chunk * 1048576; dst = Xb + (size_t)chunk * 1048576; }
  else if (chunk == 4){ src = Wq; dst = Wqb; }
  else if (chunk == 5){ src = Wk; dst = Wkb; }
  else if (chunk == 6){ src = Wv; dst = Wvb; }
  else                { src = Wo; dst = Wob; }
  int i = blockIdx.x * 256 + threadIdx.x;
  float4 v = ((const float4*)src)[i];
  u32 lo = (u32)f2bf(v.x) | ((u32)f2bf(v.y) << 16);
  u32 hi = (u32)f2bf(v.z) | ((u32)f2bf(v.w) << 16);
  ((uint2*)dst)[i] = make_uint2(lo, hi);
}

// ---------------- m97-style GEMM mainloop, 256 threads, 128x128 tile ----------------
__device__ __forceinline__ void gemm_mainloop(const u16* __restrict__ A, const u16* __restrict__ Bm,
                                              int bm, int bn, u16* As, u16* Bs,
                                              f32x4 acc[4][4]) {
  const int tid = threadIdx.x;
  const int wv = tid >> 6, lane = tid & 63, l15 = lane & 15, quad = lane >> 4;
  const int wm = wv & 1, wn = wv >> 1;

  const u16* gA[4]; const u16* gB[4];
#pragma unroll
  for (int c = 0; c < 4; ++c) {
    int idx = (wv * 4 + c) * 64 + lane;
    int r = idx >> 3;
    int cb = (idx & 7) ^ (r & 7);
    gA[c] = A  + (size_t)(bm + r) * DM + cb * 8;
    gB[c] = Bm + (size_t)(bn + r) * DM + cb * 8;
  }

  int offA[4][2], offB[4][2];
#pragma unroll
  for (int i = 0; i < 4; ++i)
#pragma unroll
    for (int h = 0; h < 2; ++h) {
      int mA = wm * 64 + i * 16 + l15;
      int mB = wn * 64 + i * 16 + l15;
      int cb = (quad + h * 4) ^ (l15 & 7);
      offA[i][h] = ((mA << 3) + cb) << 4;
      offB[i][h] = ((mB << 3) + cb) << 4;
    }

  for (int k0 = 0; k0 < DM; k0 += 64) {
#pragma unroll
    for (int c = 0; c < 4; ++c) {
      GLD16(gA[c] + k0, (char*)As + (wv * 4 + c) * 1024);
      GLD16(gB[c] + k0, (char*)Bs + (wv * 4 + c) * 1024);
    }
    __syncthreads();
    frag8 af[4][2], bf[4][2];
#pragma unroll
    for (int i = 0; i < 4; ++i) {
      af[i][0] = *(const frag8*)((const char*)As + offA[i][0]);
      af[i][1] = *(const frag8*)((const char*)As + offA[i][1]);
      bf[i][0] = *(const frag8*)((const char*)Bs + offB[i][0]);
      bf[i][1] = *(const frag8*)((const char*)Bs + offB[i][1]);
    }
#pragma unroll
    for (int h = 0; h < 2; ++h)
#pragma unroll
      for (int i = 0; i < 4; ++i)
#pragma unroll
        for (int j = 0; j < 4; ++j)
          acc[i][j] = MFMA16(af[i][h], bf[j][h], acc[i][j]);
    __syncthreads();
  }
}

__global__ __launch_bounds__(256, 3) void gemm_qkv(const u16* __restrict__ Xb,
    const u16* __restrict__ Wqb, const u16* __restrict__ Wkb, const u16* __restrict__ Wvb,
    const float* __restrict__ bq, const float* __restrict__ bk, const float* __restrict__ bv,
    u16* __restrict__ Qb, u16* __restrict__ Kb, u16* __restrict__ Vt) {
  __shared__ u16 As[8192], Bs[8192];
  const int bm = blockIdx.y * 128;
  const int which = blockIdx.x >> 3;
  const int bnl = (blockIdx.x & 7) * 128;
  const u16* W = (which == 0) ? Wqb : (which == 1) ? Wkb : Wvb;
  const float* bias = (which == 0) ? bq : (which == 1) ? bk : bv;

  f32x4 acc[4][4] = {};
  gemm_mainloop(Xb, W, bm, bnl, As, Bs, acc);

  const int tid = threadIdx.x, wv = tid >> 6, lane = tid & 63, l15 = lane & 15, quad = lane >> 4;
  const int wm = wv & 1, wn = wv >> 1;
  if (which < 2) {
    u16* O = (which == 0) ? Qb : Kb;
#pragma unroll
    for (int j = 0; j < 4; ++j) {
      int col = bnl + wn * 64 + j * 16 + l15;
      float bb = bias[col];
#pragma unroll
      for (int i = 0; i < 4; ++i) {
        int row0 = bm + wm * 64 + i * 16 + quad * 4;
#pragma unroll
        for (int r = 0; r < 4; ++r)
          O[(size_t)(row0 + r) * DM + col] = f2bf(acc[i][j][r] + bb);
      }
    }
  } else {
#pragma unroll
    for (int j = 0; j < 4; ++j) {
      int col = bnl + wn * 64 + j * 16 + l15;
      float bb = bias[col];
#pragma unroll
      for (int i = 0; i < 4; ++i) {
        int row0 = bm + wm * 64 + i * 16 + quad * 4;
        u32 lo = (u32)f2bf(acc[i][j][0] + bb) | ((u32)f2bf(acc[i][j][1] + bb) << 16);
        u32 hi = (u32)f2bf(acc[i][j][2] + bb) | ((u32)f2bf(acc[i][j][3] + bb) << 16);
        *(uint2*)&Vt[(size_t)col * BS_ + row0] = make_uint2(lo, hi);
      }
    }
  }
}

// ---------------- Wo GEMM: 64x128 tile, 512 blocks (2/CU), 256 threads ----------------
__global__ __launch_bounds__(256, 3) void gemm_wo(const u16* __restrict__ Cx,
    const u16* __restrict__ Wob, const float* __restrict__ bo, float* __restrict__ out) {
  __shared__ u16 As[4096], Bs[8192];   // A 64x64, B 128x64 (swizzled)
  const int tid = threadIdx.x;
  const int wv = tid >> 6, lane = tid & 63, l15 = lane & 15, quad = lane >> 4;
  const int bm = blockIdx.y * 64, bn = blockIdx.x * 128;

  const u16* gA[2]; const u16* gB[4];
  int ldsA[2], ldsB[4];
#pragma unroll
  for (int c = 0; c < 2; ++c) {
    int slot = c * 256 + wv * 64 + lane;
    int r = slot >> 3, cb = (slot & 7) ^ (r & 7);
    gA[c] = Cx + (size_t)(bm + r) * DM + cb * 8;
    ldsA[c] = (c * 256 + wv * 64) * 16;
  }
#pragma unroll
  for (int c = 0; c < 4; ++c) {
    int slot = c * 256 + wv * 64 + lane;
    int r = slot >> 3, cb = (slot & 7) ^ (r & 7);
    gB[c] = Wob + (size_t)(bn + r) * DM + cb * 8;
    ldsB[c] = (c * 256 + wv * 64) * 16;
  }

  int offA[2], offB[8][2];
#pragma unroll
  for (int h = 0; h < 2; ++h) {
    int rowA = wv * 16 + l15;
    offA[h] = ((rowA << 3) + ((quad + h * 4) ^ (l15 & 7))) << 4;
#pragma unroll
    for (int j = 0; j < 8; ++j) {
      int rowB = j * 16 + l15;
      offB[j][h] = ((rowB << 3) + ((quad + h * 4) ^ (l15 & 7))) << 4;
    }
  }

  f32x4 acc[8] = {};
  for (int k0 = 0; k0 < DM; k0 += 64) {
#pragma unroll
    for (int c = 0; c < 2; ++c) GLD16(gA[c] + k0, (char*)As + ldsA[c]);
#pragma unroll
    for (int c = 0; c < 4; ++c) GLD16(gB[c] + k0, (char*)Bs + ldsB[c]);
    __syncthreads();
    frag8 af0 = *(const frag8*)((const char*)As + offA[0]);
    frag8 af1 = *(const frag8*)((const char*)As + offA[1]);
#pragma unroll
    for (int j = 0; j < 8; ++j) {
      frag8 bf0 = *(const frag8*)((const char*)Bs + offB[j][0]);
      frag8 bf1 = *(const frag8*)((const char*)Bs + offB[j][1]);
      acc[j] = MFMA16(af0, bf0, acc[j]);
      acc[j] = MFMA16(af1, bf1, acc[j]);
    }
    __syncthreads();
  }

#pragma unroll
  for (int j = 0; j < 8; ++j) {
    int col = bn + j * 16 + l15;
    float bb = bo[col];
    int row0 = bm + wv * 16 + quad * 4;
#pragma unroll
    for (int r = 0; r < 4; ++r)
      out[(size_t)(row0 + r) * DM + col] = acc[j][r] + bb;
  }
}

// ---------------- Flash attention: LDS-staged + register-chained MFMA ----------------
// 1024 blocks (32 strips x 32 bh, XCD-pinned, heavy strips first), 256 thr =
// 4 waves x 16 q-rows. K [key][d] and V^T [d][key] tiles (8 KB, XOR-swizzled)
// staged via GLD16, double-buffered. S^T = MFMA(A=Kfrag, B=Qfrag) -> P^T in
// C-layout == B-layout of mfma_16x16x16; PV: O^T += MFMA(A=V^T b64 frag, P^T).
__global__ __launch_bounds__(256, 4) void attn_kernel(const u16* __restrict__ Q,
                                                      const u16* __restrict__ K,
                                                      const u16* __restrict__ Vt,
                                                      u16* __restrict__ Ctx) {
  __shared__ u16 Ks[2][4096];     // [buf][64 keys x 64 d] swizzled
  __shared__ u16 Vs[2][4096];     // [buf][64 d x 64 keys] swizzled

  const int tid = threadIdx.x, w = tid >> 6, lane = tid & 63, l15 = lane & 15, quad = lane >> 4;
  const int blk = blockIdx.x;
  const int xcd = blk & 7, slot = blk >> 3;
  const int bh = xcd + 8 * (slot & 3);
  const int strip = slot >> 2;             // 0..31, heavy (0..3) dispatch first
  const int b = bh >> 4, h = bh & 15;
  const int q0 = strip * 64;
  const int qw = q0 + w * 16;

  // Q B-frags (n = q = l15, k = d = quad*8+j) — same lane map as A
  const u16* qrow = Q + (size_t)(b * S_ + qw + l15) * DM + h * 64;
  frag8 bq0 = *(const frag8*)(qrow + quad * 8);
  frag8 bq1 = *(const frag8*)(qrow + quad * 8 + 32);

  // staging pointers (2 GLD16 per matrix per wave)
  const u16* gK[2]; const u16* gV[2]; int ldso[2];
#pragma unroll
  for (int c = 0; c < 2; ++c) {
    int sl = (w * 2 + c) * 64 + lane;
    int r = sl >> 3, cb = (sl & 7) ^ (r & 7);
    gK[c] = K  + (size_t)(b * S_ + r) * DM + h * 64 + cb * 8;        // + kt*64*DM
    gV[c] = Vt + (size_t)(h * 64 + r) * BS_ + (size_t)b * S_ + cb * 8;  // + kt*64
    ldso[c] = (w * 2 + c) * 1024;
  }

  // K A-frag LDS offsets: row = kg*16+l15 -> base(kg=0) + kg*2048 (swizzle row&7 invariant)
  int offKb[2];
#pragma unroll
  for (int hh = 0; hh < 2; ++hh)
    offKb[hh] = ((l15 << 3) + ((quad + hh * 4) ^ (l15 & 7))) << 4;
  // V^T A-frag (b64) offsets: row = nt*16+l15, key halves -> base(kg) + nt*2048
  int offVb[4];
#pragma unroll
  for (int kg = 0; kg < 4; ++kg)
    offVb[kg] = ((((l15 << 3) + (((kg << 1) | (quad >> 1)) ^ (l15 & 7))) << 4)
                 | ((quad & 1) << 3));

  const int qidx = qw + l15;
  const bool qglob = qidx < NG;

  f32x4 o[4] = {};        // O^T: row d = nt*16+quad*4+r, col q = l15
  float lsum = 0.f;

  auto activef = [&](int t) {
    int k0 = t * 64;
    return (q0 < NG) || (k0 < NG) || (k0 + 63 >= q0 - 64 && k0 <= q0 + 127);
  };
  auto nextt = [&](int cur) { int n = cur + 1; while (n < 32 && !activef(n)) ++n; return n; };
  auto stage = [&](int t, int buf) {
#pragma unroll
    for (int c = 0; c < 2; ++c) {
      GLD16(gK[c] + (size_t)t * 64 * DM, (char*)Ks[buf] + ldso[c]);
      GLD16(gV[c] + t * 64,              (char*)Vs[buf] + ldso[c]);
    }
  };

  int kt = 0, p = 0;                        // tile 0 always active (global cols)
  stage(0, 0);
  for (;;) {
    int ktn = nextt(kt);
    bool more = ktn < 32;
    __syncthreads();                        // buf[p] ready; buf[p^1] free
    if (more) stage(ktn, p ^ 1);

    const char* kb_ = (const char*)Ks[p];
    const char* vb_ = (const char*)Vs[p];

    // S^T: 4 C-frags (rows key = kg*16+quad*4+r, col q = l15)
    f32x4 st[4] = {};
#pragma unroll
    for (int kg = 0; kg < 4; ++kg) {
      frag8 ak0 = *(const frag8*)(kb_ + offKb[0] + kg * 2048);
      frag8 ak1 = *(const frag8*)(kb_ + offKb[1] + kg * 2048);
      st[kg] = MFMA16(ak0, bq0, st[kg]);
      st[kg] = MFMA16(ak1, bq1, st[kg]);
    }

    const int k0 = kt * 64;
    const bool domask = (strip > 2) && (kt > 2);   // global rows/cols need no mask
    frag4 pk[4];
    if (domask) {
#pragma unroll
      for (int kg = 0; kg < 4; ++kg) {
        float pr[4];
#pragma unroll
        for (int r = 0; r < 4; ++r) {
          int kc = k0 + kg * 16 + quad * 4 + r;
          int d = qidx - kc;
          bool act = ((unsigned)(d + 64) <= 128u) || qglob || (kc < NG);
          float pv = EXP2(act ? st[kg][r] * SCL2 : NEGF);
          pr[r] = pv; lsum += pv;
        }
        pk[kg] = frag4{(short)f2bfc(pr[0]), (short)f2bfc(pr[1]),
                       (short)f2bfc(pr[2]), (short)f2bfc(pr[3])};
      }
    } else {
#pragma unroll
      for (int kg = 0; kg < 4; ++kg) {
        float pr[4];
#pragma unroll
        for (int r = 0; r < 4; ++r) {
          float pv = EXP2(st[kg][r] * SCL2);
          pr[r] = pv; lsum += pv;
        }
        pk[kg] = frag4{(short)f2bfc(pr[0]), (short)f2bfc(pr[1]),
                       (short)f2bfc(pr[2]), (short)f2bfc(pr[3])};
      }
    }

    // O^T += V^T . P^T — P from registers, V^T via b64 LDS frags
#pragma unroll
    for (int nt = 0; nt < 4; ++nt)
#pragma unroll
      for (int kg = 0; kg < 4; ++kg) {
        frag4 av = *(const frag4*)(vb_ + offVb[kg] + nt * 2048);
        o[nt] = mfma_16x16x16_bf16(av, pk[kg], o[nt]);
      }

    if (!more) break;
    kt = ktn; p ^= 1;
  }

  lsum += __shfl_xor(lsum, 16);
  lsum += __shfl_xor(lsum, 32);
  float inv = 1.0f / lsum;

  u16* crow = Ctx + (size_t)((size_t)b * S_ + qw + l15) * DM + h * 64;
#pragma unroll
  for (int nt = 0; nt < 4; ++nt) {
    u32 lo = (u32)f2bf(o[nt][0] * inv) | ((u32)f2bf(o[nt][1] * inv) << 16);
    u32 hi = (u32)f2bf(o[nt][2] * inv) | ((u32)f2bf(o[nt][3] * inv) << 16);
    *(uint2*)&crow[nt * 16 + quad * 4] = make_uint2(lo, hi);
  }
}

// ---------------- launch ----------------
extern "C" void kernel_launch(void* const* d_in, const int* in_sizes, int n_in,
                              void* d_out, int out_size, void* d_ws, size_t ws_size,
                              hipStream_t stream) {
  const float* X  = (const float*)d_in[0];
  const float* Wq = (const float*)d_in[1];
  const float* bq = (const float*)d_in[2];
  const float* Wk = (const float*)d_in[3];
  const float* bk = (const float*)d_in[4];
  const float* Wv = (const float*)d_in[5];
  const float* bv = (const float*)d_in[6];
  const float* Wo = (const float*)d_in[7];
  const float* bo = (const float*)d_in[8];
  float* out = (float*)d_out;

  u16* ws = (u16*)d_ws;
  const size_t NX = (size_t)BS_ * DM;
  const size_t NW = (size_t)DM * DM;
  u16* Xb  = ws;
  u16* Wqb = Xb + NX;
  u16* Wkb = Wqb + NW;
  u16* Wvb = Wkb + NW;
  u16* Wob = Wvb + NW;
  u16* Qb  = Wob + NW;
  u16* Kb  = Qb + NX;
  u16* Vt  = Kb + NX;
  u16* Cx  = Vt + NX;

  cvt_all<<<dim3(1024, 8), 256, 0, stream>>>(X, Wq, Wk, Wv, Wo, Xb, Wqb, Wkb, Wvb, Wob);
  gemm_qkv<<<dim3(24, 32), 256, 0, stream>>>(Xb, Wqb, Wkb, Wvb, bq, bk, bv, Qb, Kb, Vt);
  attn_kernel<<<1024, 256, 0, stream>>>(Qb, Kb, Vt, Cx);
  gemm_wo<<<dim3(8, 64), 256, 0, stream>>>(Cx, Wob, bo, out);
}

// Round 10
// 169.906 us; speedup vs baseline: 1.4964x; 1.0588x over previous
//
#include <hip/hip_runtime.h>

// LongformerAttention MI355X — Round 9.
// attn: split-K heavy strips (4 segs x 8 tiles -> Op/Lp partials + combine) to
// kill the heavy-block tail; improved LDS swizzle (row>>3 mixed in) to kill
// ds_read_b64 bank conflicts; Q pre-scaled by SCL2 in qkv epilogue; lsum via
// ones-MFMA (matrix pipe) instead of VALU adds. gemm/cvt otherwise unchanged.

#define B_   2
#define S_   2048
#define DM   1024
#define H_   16
#define NG   204                     // max(1, int(S*0.1))
#define BS_  4096                    // B_*S_
#define SCL2 0.1803368801111204f     // (1/sqrt(64)) * log2(e)  — folded into Q
#define NEGF -3.0e38f

typedef unsigned short u16;
typedef unsigned int   u32;
typedef __attribute__((ext_vector_type(8))) short frag8;   // 8 x bf16
typedef __attribute__((ext_vector_type(4))) short frag4;   // 4 x bf16
typedef __attribute__((ext_vector_type(4))) float f32x4;

#define MFMA16(A, Bf, C) __builtin_amdgcn_mfma_f32_16x16x32_bf16((A), (Bf), (C), 0, 0, 0)

__device__ __forceinline__ f32x4 mfma_16x16x16_bf16(frag4 a, frag4 b, f32x4 c) {
#if defined(__HIP_DEVICE_COMPILE__)
  return __builtin_amdgcn_mfma_f32_16x16x16bf16_1k(a, b, c, 0, 0, 0);
#else
  (void)a; (void)b;
  return c;
#endif
}

#define GLD16(g, l)                                                              \
  __builtin_amdgcn_global_load_lds((const __attribute__((address_space(1))) u32*)(g), \
                                   (__attribute__((address_space(3))) u32*)(l), 16, 0, 0)
#define EXP2(x) exp2f(x)

__device__ __forceinline__ u16 f2bf(float f) {          // RNE (epilogues/GEMM)
  union { float f; u32 u; } c; c.f = f;
  u32 u = c.u + 0x7fffu + ((c.u >> 16) & 1u);
  return (u16)(u >> 16);
}
__device__ __forceinline__ u16 f2bfc(float f) {         // cheap RN (P inner loop)
  union { float f; u32 u; } c; c.f = f;
  return (u16)((c.u + 0x8000u) >> 16);
}

// ---------------- fp32 -> bf16 convert, all buffers in one launch ----------------
__global__ void cvt_all(const float* __restrict__ X,  const float* __restrict__ Wq,
                        const float* __restrict__ Wk, const float* __restrict__ Wv,
                        const float* __restrict__ Wo,
                        u16* Xb, u16* Wqb, u16* Wkb, u16* Wvb, u16* Wob) {
  const int chunk = blockIdx.y;
  const float* src; u16* dst;
  if (chunk < 4)      { src = X + (size_t)chunk * 1048576; dst = Xb + (size_t)chunk * 1048576; }
  else if (chunk == 4){ src = Wq; dst = Wqb; }
  else if (chunk == 5){ src = Wk; dst = Wkb; }
  else if (chunk == 6){ src = Wv; dst = Wvb; }
  else                { src = Wo; dst = Wob; }
  int i = blockIdx.x * 256 + threadIdx.x;
  float4 v = ((const float4*)src)[i];
  u32 lo = (u32)f2bf(v.x) | ((u32)f2bf(v.y) << 16);
  u32 hi = (u32)f2bf(v.z) | ((u32)f2bf(v.w) << 16);
  ((uint2*)dst)[i] = make_uint2(lo, hi);
}

// ---------------- m97-style GEMM mainloop, 256 threads, 128x128 tile ----------------
__device__ __forceinline__ void gemm_mainloop(const u16* __restrict__ A, const u16* __restrict__ Bm,
                                              int bm, int bn, u16* As, u16* Bs,
                                              f32x4 acc[4][4]) {
  const int tid = threadIdx.x;
  const int wv = tid >> 6, lane = tid & 63, l15 = lane & 15, quad = lane >> 4;
  const int wm = wv & 1, wn = wv >> 1;

  const u16* gA[4]; const u16* gB[4];
#pragma unroll
  for (int c = 0; c < 4; ++c) {
    int idx = (wv * 4 + c) * 64 + lane;
    int r = idx >> 3;
    int cb = (idx & 7) ^ (r & 7);
    gA[c] = A  + (size_t)(bm + r) * DM + cb * 8;
    gB[c] = Bm + (size_t)(bn + r) * DM + cb * 8;
  }

  int offA[4][2], offB[4][2];
#pragma unroll
  for (int i = 0; i < 4; ++i)
#pragma unroll
    for (int h = 0; h < 2; ++h) {
      int mA = wm * 64 + i * 16 + l15;
      int mB = wn * 64 + i * 16 + l15;
      int cb = (quad + h * 4) ^ (l15 & 7);
      offA[i][h] = ((mA << 3) + cb) << 4;
      offB[i][h] = ((mB << 3) + cb) << 4;
    }

  for (int k0 = 0; k0 < DM; k0 += 64) {
#pragma unroll
    for (int c = 0; c < 4; ++c) {
      GLD16(gA[c] + k0, (char*)As + (wv * 4 + c) * 1024);
      GLD16(gB[c] + k0, (char*)Bs + (wv * 4 + c) * 1024);
    }
    __syncthreads();
    frag8 af[4][2], bf[4][2];
#pragma unroll
    for (int i = 0; i < 4; ++i) {
      af[i][0] = *(const frag8*)((const char*)As + offA[i][0]);
      af[i][1] = *(const frag8*)((const char*)As + offA[i][1]);
      bf[i][0] = *(const frag8*)((const char*)Bs + offB[i][0]);
      bf[i][1] = *(const frag8*)((const char*)Bs + offB[i][1]);
    }
#pragma unroll
    for (int h = 0; h < 2; ++h)
#pragma unroll
      for (int i = 0; i < 4; ++i)
#pragma unroll
        for (int j = 0; j < 4; ++j)
          acc[i][j] = MFMA16(af[i][h], bf[j][h], acc[i][j]);
    __syncthreads();
  }
}

__global__ __launch_bounds__(256, 3) void gemm_qkv(const u16* __restrict__ Xb,
    const u16* __restrict__ Wqb, const u16* __restrict__ Wkb, const u16* __restrict__ Wvb,
    const float* __restrict__ bq, const float* __restrict__ bk, const float* __restrict__ bv,
    u16* __restrict__ Qb, u16* __restrict__ Kb, u16* __restrict__ Vt) {
  __shared__ u16 As[8192], Bs[8192];
  const int bm = blockIdx.y * 128;
  const int which = blockIdx.x >> 3;
  const int bnl = (blockIdx.x & 7) * 128;
  const u16* W = (which == 0) ? Wqb : (which == 1) ? Wkb : Wvb;
  const float* bias = (which == 0) ? bq : (which == 1) ? bk : bv;

  f32x4 acc[4][4] = {};
  gemm_mainloop(Xb, W, bm, bnl, As, Bs, acc);

  const int tid = threadIdx.x, wv = tid >> 6, lane = tid & 63, l15 = lane & 15, quad = lane >> 4;
  const int wm = wv & 1, wn = wv >> 1;
  if (which < 2) {
    u16* O = (which == 0) ? Qb : Kb;
    const float scl = (which == 0) ? SCL2 : 1.0f;   // fold softmax scale into Q
#pragma unroll
    for (int j = 0; j < 4; ++j) {
      int col = bnl + wn * 64 + j * 16 + l15;
      float bb = bias[col];
#pragma unroll
      for (int i = 0; i < 4; ++i) {
        int row0 = bm + wm * 64 + i * 16 + quad * 4;
#pragma unroll
        for (int r = 0; r < 4; ++r)
          O[(size_t)(row0 + r) * DM + col] = f2bf((acc[i][j][r] + bb) * scl);
      }
    }
  } else {
#pragma unroll
    for (int j = 0; j < 4; ++j) {
      int col = bnl + wn * 64 + j * 16 + l15;
      float bb = bias[col];
#pragma unroll
      for (int i = 0; i < 4; ++i) {
        int row0 = bm + wm * 64 + i * 16 + quad * 4;
        u32 lo = (u32)f2bf(acc[i][j][0] + bb) | ((u32)f2bf(acc[i][j][1] + bb) << 16);
        u32 hi = (u32)f2bf(acc[i][j][2] + bb) | ((u32)f2bf(acc[i][j][3] + bb) << 16);
        *(uint2*)&Vt[(size_t)col * BS_ + row0] = make_uint2(lo, hi);
      }
    }
  }
}

// ---------------- Wo GEMM: 64x128 tile, 512 blocks (2/CU), 256 threads ----------------
__global__ __launch_bounds__(256, 3) void gemm_wo(const u16* __restrict__ Cx,
    const u16* __restrict__ Wob, const float* __restrict__ bo, float* __restrict__ out) {
  __shared__ u16 As[4096], Bs[8192];   // A 64x64, B 128x64 (swizzled)
  const int tid = threadIdx.x;
  const int wv = tid >> 6, lane = tid & 63, l15 = lane & 15, quad = lane >> 4;
  const int bm = blockIdx.y * 64, bn = blockIdx.x * 128;

  const u16* gA[2]; const u16* gB[4];
  int ldsA[2], ldsB[4];
#pragma unroll
  for (int c = 0; c < 2; ++c) {
    int slot = c * 256 + wv * 64 + lane;
    int r = slot >> 3, cb = (slot & 7) ^ (r & 7);
    gA[c] = Cx + (size_t)(bm + r) * DM + cb * 8;
    ldsA[c] = (c * 256 + wv * 64) * 16;
  }
#pragma unroll
  for (int c = 0; c < 4; ++c) {
    int slot = c * 256 + wv * 64 + lane;
    int r = slot >> 3, cb = (slot & 7) ^ (r & 7);
    gB[c] = Wob + (size_t)(bn + r) * DM + cb * 8;
    ldsB[c] = (c * 256 + wv * 64) * 16;
  }

  int offA[2], offB[8][2];
#pragma unroll
  for (int h = 0; h < 2; ++h) {
    int rowA = wv * 16 + l15;
    offA[h] = ((rowA << 3) + ((quad + h * 4) ^ (l15 & 7))) << 4;
#pragma unroll
    for (int j = 0; j < 8; ++j) {
      int rowB = j * 16 + l15;
      offB[j][h] = ((rowB << 3) + ((quad + h * 4) ^ (l15 & 7))) << 4;
    }
  }

  f32x4 acc[8] = {};
  for (int k0 = 0; k0 < DM; k0 += 64) {
#pragma unroll
    for (int c = 0; c < 2; ++c) GLD16(gA[c] + k0, (char*)As + ldsA[c]);
#pragma unroll
    for (int c = 0; c < 4; ++c) GLD16(gB[c] + k0, (char*)Bs + ldsB[c]);
    __syncthreads();
    frag8 af0 = *(const frag8*)((const char*)As + offA[0]);
    frag8 af1 = *(const frag8*)((const char*)As + offA[1]);
#pragma unroll
    for (int j = 0; j < 8; ++j) {
      frag8 bf0 = *(const frag8*)((const char*)Bs + offB[j][0]);
      frag8 bf1 = *(const frag8*)((const char*)Bs + offB[j][1]);
      acc[j] = MFMA16(af0, bf0, acc[j]);
      acc[j] = MFMA16(af1, bf1, acc[j]);
    }
    __syncthreads();
  }

#pragma unroll
  for (int j = 0; j < 8; ++j) {
    int col = bn + j * 16 + l15;
    float bb = bo[col];
    int row0 = bm + wv * 16 + quad * 4;
#pragma unroll
    for (int r = 0; r < 4; ++r)
      out[(size_t)(row0 + r) * DM + col] = acc[j][r] + bb;
  }
}

// ---------------- Flash attention: LDS-staged, chained MFMA, split-K heavy ----------------
// Units per bh: 16 heavy-split (strips 0..3 x 4 segs of 8 tiles, fp32 partials)
// + 28 light (strips 4..31, tile-skip loop, direct Ctx). Grid 44*32 = 1408;
// bh = blk&31 (XCD-pinned via bh&7), unit = blk>>5 (heavy dispatch first).
__global__ __launch_bounds__(256) void attn_kernel(const u16* __restrict__ Q,
                                                   const u16* __restrict__ K,
                                                   const u16* __restrict__ Vt,
                                                   u16* __restrict__ Ctx,
                                                   float* __restrict__ Op,
                                                   float* __restrict__ Lp) {
  __shared__ u16 Ks[2][4096];     // [buf][64 keys x 64 d] swizzled
  __shared__ u16 Vs[2][4096];     // [buf][64 d x 64 keys] swizzled

  const int tid = threadIdx.x, w = tid >> 6, lane = tid & 63, l15 = lane & 15, quad = lane >> 4;
  const int blk = blockIdx.x;
  const int bh = blk & 31, unit = blk >> 5;
  const int b = bh >> 4, h = bh & 15;
  const bool heavy = unit < 16;
  const int strip = heavy ? (unit >> 2) : (unit - 12);   // heavy 0..3, light 4..31
  const int q0 = strip * 64;
  const int qw = q0 + w * 16;

  // Q B-frags (n = q = l15, k = d = quad*8+j); Q already carries SCL2
  const u16* qrow = Q + (size_t)(b * S_ + qw + l15) * DM + h * 64;
  frag8 bq0 = *(const frag8*)(qrow + quad * 8);
  frag8 bq1 = *(const frag8*)(qrow + quad * 8 + 32);

  // staging pointers; swizzle f(r) = (r&7) ^ (((r>>3)&1)<<2)
  const u16* gK[2]; const u16* gV[2]; int ldso[2];
#pragma unroll
  for (int c = 0; c < 2; ++c) {
    int sl = (w * 2 + c) * 64 + lane;
    int r = sl >> 3;
    int fr = (r & 7) ^ (((r >> 3) & 1) << 2);
    int cb = (sl & 7) ^ fr;
    gK[c] = K  + (size_t)(b * S_ + r) * DM + h * 64 + cb * 8;        // + kt*64*DM
    gV[c] = Vt + (size_t)(h * 64 + r) * BS_ + (size_t)b * S_ + cb * 8;  // + kt*64
    ldso[c] = (w * 2 + c) * 1024;
  }

  const int fl = (l15 & 7) ^ (((l15 >> 3) & 1) << 2);   // f(row) for row%16 = l15
  int offKb[2];
#pragma unroll
  for (int hh = 0; hh < 2; ++hh)
    offKb[hh] = ((l15 << 3) + ((quad + hh * 4) ^ fl)) << 4;
  int offVb[4];
#pragma unroll
  for (int kg = 0; kg < 4; ++kg)
    offVb[kg] = ((((l15 << 3) + ((((kg << 1) | (quad >> 1))) ^ fl)) << 4)
                 | ((quad & 1) << 3));

  const int qidx = qw + l15;
  const bool qglob = qidx < NG;
  const frag4 ones = {(short)0x3F80, (short)0x3F80, (short)0x3F80, (short)0x3F80};

  f32x4 o[4] = {};        // O^T: row d = nt*16+quad*4+r, col q = l15
  f32x4 o_l = {};         // lsum via ones-MFMA: o_l[0] = sum_k P^T[k][q=l15]

  auto stage = [&](int t, int buf) {
#pragma unroll
    for (int c = 0; c < 2; ++c) {
      GLD16(gK[c] + (size_t)t * 64 * DM, (char*)Ks[buf] + ldso[c]);
      GLD16(gV[c] + t * 64,              (char*)Vs[buf] + ldso[c]);
    }
  };

  auto step = [&](int kt, int p, bool domask) {
    const char* kb_ = (const char*)Ks[p];
    const char* vb_ = (const char*)Vs[p];
    f32x4 st[4] = {};
#pragma unroll
    for (int kg = 0; kg < 4; ++kg) {
      frag8 ak0 = *(const frag8*)(kb_ + offKb[0] + kg * 2048);
      frag8 ak1 = *(const frag8*)(kb_ + offKb[1] + kg * 2048);
      st[kg] = MFMA16(ak0, bq0, st[kg]);
      st[kg] = MFMA16(ak1, bq1, st[kg]);
    }
    const int k0 = kt * 64;
    frag4 pk[4];
    if (domask) {
#pragma unroll
      for (int kg = 0; kg < 4; ++kg) {
        float pr[4];
#pragma unroll
        for (int r = 0; r < 4; ++r) {
          int kc = k0 + kg * 16 + quad * 4 + r;
          int d = qidx - kc;
          bool act = ((unsigned)(d + 64) <= 128u) || qglob || (kc < NG);
          pr[r] = EXP2(act ? st[kg][r] : NEGF);
        }
        pk[kg] = frag4{(short)f2bfc(pr[0]), (short)f2bfc(pr[1]),
                       (short)f2bfc(pr[2]), (short)f2bfc(pr[3])};
      }
    } else {
#pragma unroll
      for (int kg = 0; kg < 4; ++kg) {
        float pr[4];
#pragma unroll
        for (int r = 0; r < 4; ++r) pr[r] = EXP2(st[kg][r]);
        pk[kg] = frag4{(short)f2bfc(pr[0]), (short)f2bfc(pr[1]),
                       (short)f2bfc(pr[2]), (short)f2bfc(pr[3])};
      }
    }
#pragma unroll
    for (int kg = 0; kg < 4; ++kg) {
      o_l = mfma_16x16x16_bf16(ones, pk[kg], o_l);   // lsum on the MFMA pipe
#pragma unroll
      for (int nt = 0; nt < 4; ++nt) {
        frag4 av = *(const frag4*)(vb_ + offVb[kg] + nt * 2048);
        o[nt] = mfma_16x16x16_bf16(av, pk[kg], o[nt]);
      }
    }
  };

  if (heavy) {
    const int seg = unit & 3;
    const int kt0 = seg * 8;
    const bool dm = (strip == 3);         // rows 192..255 straddle NG cutoff
    int p = 0;
    stage(kt0, 0);
#pragma unroll 1
    for (int tt = 0; tt < 8; ++tt) {
      __syncthreads();
      if (tt < 7) stage(kt0 + tt + 1, p ^ 1);
      step(kt0 + tt, p, dm && (kt0 + tt > 2));
      p ^= 1;
    }
    // partials: Op[unit][q 0..63][d 0..63] fp32, Lp[unit][q 0..63]
    float* op = Op + ((size_t)((bh * 4 + strip) * 4 + seg)) * 4096;
    float* lp = Lp + ((size_t)((bh * 4 + strip) * 4 + seg)) * 64;
    if (quad == 0) lp[w * 16 + l15] = o_l[0];
#pragma unroll
    for (int nt = 0; nt < 4; ++nt)
      *(float4*)&op[(w * 16 + l15) * 64 + nt * 16 + quad * 4] =
          make_float4(o[nt][0], o[nt][1], o[nt][2], o[nt][3]);
    return;
  }

  // light path: strips 4..31, tile-skip loop
  auto activef = [&](int t) {
    int k0 = t * 64;
    return (k0 < NG) || (k0 + 63 >= q0 - 64 && k0 <= q0 + 127);
  };
  auto nextt = [&](int cur) { int n = cur + 1; while (n < 32 && !activef(n)) ++n; return n; };

  int kt = 0, p = 0;                      // tile 0 always active (global cols)
  stage(0, 0);
  for (;;) {
    int ktn = nextt(kt);
    bool more = ktn < 32;
    __syncthreads();
    if (more) stage(ktn, p ^ 1);
    step(kt, p, kt > 2);
    if (!more) break;
    kt = ktn; p ^= 1;
  }

  float inv = 1.0f / o_l[0];
  u16* crow = Ctx + (size_t)((size_t)b * S_ + qw + l15) * DM + h * 64;
#pragma unroll
  for (int nt = 0; nt < 4; ++nt) {
    u32 lo = (u32)f2bf(o[nt][0] * inv) | ((u32)f2bf(o[nt][1] * inv) << 16);
    u32 hi = (u32)f2bf(o[nt][2] * inv) | ((u32)f2bf(o[nt][3] * inv) << 16);
    *(uint2*)&crow[nt * 16 + quad * 4] = make_uint2(lo, hi);
  }
}

// ---------------- combine split-K partials -> Ctx rows 0..255 ----------------
// 128 blocks (4 strips x 32 bh), 256 thr: row = t>>2 (q), 16 d-cols each.
__global__ __launch_bounds__(256) void combine_kernel(const float* __restrict__ Op,
                                                      const float* __restrict__ Lp,
                                                      u16* __restrict__ Ctx) {
  const int blk = blockIdx.x;
  const int bh = blk & 31, strip = blk >> 5;
  const int b = bh >> 4, h = bh & 15;
  const int t = threadIdx.x;
  const int row = t >> 2, colg = (t & 3) * 16;

  const float* opb = Op + ((size_t)(bh * 4 + strip) * 4) * 4096;
  const float* lpb = Lp + ((size_t)(bh * 4 + strip) * 4) * 64;

  float l = lpb[row] + lpb[64 + row] + lpb[128 + row] + lpb[192 + row];
  float acc[16];
#pragma unroll
  for (int e = 0; e < 16; ++e) acc[e] = opb[row * 64 + colg + e];
#pragma unroll
  for (int seg = 1; seg < 4; ++seg)
#pragma unroll
    for (int e = 0; e < 16; ++e) acc[e] += opb[seg * 4096 + row * 64 + colg + e];

  float inv = 1.0f / l;
  u32 pk[8];
#pragma unroll
  for (int p = 0; p < 8; ++p)
    pk[p] = (u32)f2bf(acc[2 * p] * inv) | ((u32)f2bf(acc[2 * p + 1] * inv) << 16);
  u16* dst = Ctx + (size_t)((size_t)b * S_ + strip * 64 + row) * DM + h * 64 + colg;
  *(uint4*)dst       = make_uint4(pk[0], pk[1], pk[2], pk[3]);
  *(uint4*)(dst + 8) = make_uint4(pk[4], pk[5], pk[6], pk[7]);
}

// ---------------- launch ----------------
extern "C" void kernel_launch(void* const* d_in, const int* in_sizes, int n_in,
                              void* d_out, int out_size, void* d_ws, size_t ws_size,
                              hipStream_t stream) {
  const float* X  = (const float*)d_in[0];
  const float* Wq = (const float*)d_in[1];
  const float* bq = (const float*)d_in[2];
  const float* Wk = (const float*)d_in[3];
  const float* bk = (const float*)d_in[4];
  const float* Wv = (const float*)d_in[5];
  const float* bv = (const float*)d_in[6];
  const float* Wo = (const float*)d_in[7];
  const float* bo = (const float*)d_in[8];
  float* out = (float*)d_out;

  u16* ws = (u16*)d_ws;
  const size_t NX = (size_t)BS_ * DM;
  const size_t NW = (size_t)DM * DM;
  u16* Xb  = ws;
  u16* Wqb = Xb + NX;
  u16* Wkb = Wqb + NW;
  u16* Wvb = Wkb + NW;
  u16* Wob = Wvb + NW;
  u16* Qb  = Wob + NW;
  u16* Kb  = Qb + NX;
  u16* Vt  = Kb + NX;
  u16* Cx  = Vt + NX;
  float* Op = (float*)(Cx + NX);               // 32*4*4*4096 = 2.1M floats (8 MB)
  float* Lp = Op + (size_t)32 * 4 * 4 * 4096;  // 32k floats

  cvt_all<<<dim3(1024, 8), 256, 0, stream>>>(X, Wq, Wk, Wv, Wo, Xb, Wqb, Wkb, Wvb, Wob);
  gemm_qkv<<<dim3(24, 32), 256, 0, stream>>>(Xb, Wqb, Wkb, Wvb, bq, bk, bv, Qb, Kb, Vt);
  attn_kernel<<<44 * 32, 256, 0, stream>>>(Qb, Kb, Vt, Cx, Op, Lp);
  combine_kernel<<<128, 256, 0, stream>>>(Op, Lp, Cx);
  gemm_wo<<<dim3(8, 64), 256, 0, stream>>>(Cx, Wob, bo, out);
}

// Round 11
// 169.553 us; speedup vs baseline: 1.4995x; 1.0021x over previous
//
#include <hip/hip_runtime.h>

// LongformerAttention MI355X — Round 10.
// attn: 128-q blocks (each wave = two 16-q groups sharing one staged K/V tile)
// -> staging/barrier cost per unit work halved; 704 blocks fully co-resident
// at 3/CU (no tail). Heavy strips (q<256) keep 4-way split-K + combine.
// cvt/gemm_qkv/gemm_wo unchanged from Round 9.

#define B_   2
#define S_   2048
#define DM   1024
#define H_   16
#define NG   204                     // max(1, int(S*0.1))
#define BS_  4096                    // B_*S_
#define SCL2 0.1803368801111204f     // (1/sqrt(64)) * log2(e)  — folded into Q
#define NEGF -3.0e38f

typedef unsigned short u16;
typedef unsigned int   u32;
typedef __attribute__((ext_vector_type(8))) short frag8;   // 8 x bf16
typedef __attribute__((ext_vector_type(4))) short frag4;   // 4 x bf16
typedef __attribute__((ext_vector_type(4))) float f32x4;

#define MFMA16(A, Bf, C) __builtin_amdgcn_mfma_f32_16x16x32_bf16((A), (Bf), (C), 0, 0, 0)

__device__ __forceinline__ f32x4 mfma_16x16x16_bf16(frag4 a, frag4 b, f32x4 c) {
#if defined(__HIP_DEVICE_COMPILE__)
  return __builtin_amdgcn_mfma_f32_16x16x16bf16_1k(a, b, c, 0, 0, 0);
#else
  (void)a; (void)b;
  return c;
#endif
}

#define GLD16(g, l)                                                              \
  __builtin_amdgcn_global_load_lds((const __attribute__((address_space(1))) u32*)(g), \
                                   (__attribute__((address_space(3))) u32*)(l), 16, 0, 0)
#define EXP2(x) exp2f(x)

__device__ __forceinline__ u16 f2bf(float f) {          // RNE (epilogues/GEMM)
  union { float f; u32 u; } c; c.f = f;
  u32 u = c.u + 0x7fffu + ((c.u >> 16) & 1u);
  return (u16)(u >> 16);
}
__device__ __forceinline__ u16 f2bfc(float f) {         // cheap RN (P inner loop)
  union { float f; u32 u; } c; c.f = f;
  return (u16)((c.u + 0x8000u) >> 16);
}

// ---------------- fp32 -> bf16 convert, all buffers in one launch ----------------
__global__ void cvt_all(const float* __restrict__ X,  const float* __restrict__ Wq,
                        const float* __restrict__ Wk, const float* __restrict__ Wv,
                        const float* __restrict__ Wo,
                        u16* Xb, u16* Wqb, u16* Wkb, u16* Wvb, u16* Wob) {
  const int chunk = blockIdx.y;
  const float* src; u16* dst;
  if (chunk < 4)      { src = X + (size_t)chunk * 1048576; dst = Xb + (size_t)chunk * 1048576; }
  else if (chunk == 4){ src = Wq; dst = Wqb; }
  else if (chunk == 5){ src = Wk; dst = Wkb; }
  else if (chunk == 6){ src = Wv; dst = Wvb; }
  else                { src = Wo; dst = Wob; }
  int i = blockIdx.x * 256 + threadIdx.x;
  float4 v = ((const float4*)src)[i];
  u32 lo = (u32)f2bf(v.x) | ((u32)f2bf(v.y) << 16);
  u32 hi = (u32)f2bf(v.z) | ((u32)f2bf(v.w) << 16);
  ((uint2*)dst)[i] = make_uint2(lo, hi);
}

// ---------------- m97-style GEMM mainloop, 256 threads, 128x128 tile ----------------
__device__ __forceinline__ void gemm_mainloop(const u16* __restrict__ A, const u16* __restrict__ Bm,
                                              int bm, int bn, u16* As, u16* Bs,
                                              f32x4 acc[4][4]) {
  const int tid = threadIdx.x;
  const int wv = tid >> 6, lane = tid & 63, l15 = lane & 15, quad = lane >> 4;
  const int wm = wv & 1, wn = wv >> 1;

  const u16* gA[4]; const u16* gB[4];
#pragma unroll
  for (int c = 0; c < 4; ++c) {
    int idx = (wv * 4 + c) * 64 + lane;
    int r = idx >> 3;
    int cb = (idx & 7) ^ (r & 7);
    gA[c] = A  + (size_t)(bm + r) * DM + cb * 8;
    gB[c] = Bm + (size_t)(bn + r) * DM + cb * 8;
  }

  int offA[4][2], offB[4][2];
#pragma unroll
  for (int i = 0; i < 4; ++i)
#pragma unroll
    for (int h = 0; h < 2; ++h) {
      int mA = wm * 64 + i * 16 + l15;
      int mB = wn * 64 + i * 16 + l15;
      int cb = (quad + h * 4) ^ (l15 & 7);
      offA[i][h] = ((mA << 3) + cb) << 4;
      offB[i][h] = ((mB << 3) + cb) << 4;
    }

  for (int k0 = 0; k0 < DM; k0 += 64) {
#pragma unroll
    for (int c = 0; c < 4; ++c) {
      GLD16(gA[c] + k0, (char*)As + (wv * 4 + c) * 1024);
      GLD16(gB[c] + k0, (char*)Bs + (wv * 4 + c) * 1024);
    }
    __syncthreads();
    frag8 af[4][2], bf[4][2];
#pragma unroll
    for (int i = 0; i < 4; ++i) {
      af[i][0] = *(const frag8*)((const char*)As + offA[i][0]);
      af[i][1] = *(const frag8*)((const char*)As + offA[i][1]);
      bf[i][0] = *(const frag8*)((const char*)Bs + offB[i][0]);
      bf[i][1] = *(const frag8*)((const char*)Bs + offB[i][1]);
    }
#pragma unroll
    for (int h = 0; h < 2; ++h)
#pragma unroll
      for (int i = 0; i < 4; ++i)
#pragma unroll
        for (int j = 0; j < 4; ++j)
          acc[i][j] = MFMA16(af[i][h], bf[j][h], acc[i][j]);
    __syncthreads();
  }
}

__global__ __launch_bounds__(256, 3) void gemm_qkv(const u16* __restrict__ Xb,
    const u16* __restrict__ Wqb, const u16* __restrict__ Wkb, const u16* __restrict__ Wvb,
    const float* __restrict__ bq, const float* __restrict__ bk, const float* __restrict__ bv,
    u16* __restrict__ Qb, u16* __restrict__ Kb, u16* __restrict__ Vt) {
  __shared__ u16 As[8192], Bs[8192];
  const int bm = blockIdx.y * 128;
  const int which = blockIdx.x >> 3;
  const int bnl = (blockIdx.x & 7) * 128;
  const u16* W = (which == 0) ? Wqb : (which == 1) ? Wkb : Wvb;
  const float* bias = (which == 0) ? bq : (which == 1) ? bk : bv;

  f32x4 acc[4][4] = {};
  gemm_mainloop(Xb, W, bm, bnl, As, Bs, acc);

  const int tid = threadIdx.x, wv = tid >> 6, lane = tid & 63, l15 = lane & 15, quad = lane >> 4;
  const int wm = wv & 1, wn = wv >> 1;
  if (which < 2) {
    u16* O = (which == 0) ? Qb : Kb;
    const float scl = (which == 0) ? SCL2 : 1.0f;   // fold softmax scale into Q
#pragma unroll
    for (int j = 0; j < 4; ++j) {
      int col = bnl + wn * 64 + j * 16 + l15;
      float bb = bias[col];
#pragma unroll
      for (int i = 0; i < 4; ++i) {
        int row0 = bm + wm * 64 + i * 16 + quad * 4;
#pragma unroll
        for (int r = 0; r < 4; ++r)
          O[(size_t)(row0 + r) * DM + col] = f2bf((acc[i][j][r] + bb) * scl);
      }
    }
  } else {
#pragma unroll
    for (int j = 0; j < 4; ++j) {
      int col = bnl + wn * 64 + j * 16 + l15;
      float bb = bias[col];
#pragma unroll
      for (int i = 0; i < 4; ++i) {
        int row0 = bm + wm * 64 + i * 16 + quad * 4;
        u32 lo = (u32)f2bf(acc[i][j][0] + bb) | ((u32)f2bf(acc[i][j][1] + bb) << 16);
        u32 hi = (u32)f2bf(acc[i][j][2] + bb) | ((u32)f2bf(acc[i][j][3] + bb) << 16);
        *(uint2*)&Vt[(size_t)col * BS_ + row0] = make_uint2(lo, hi);
      }
    }
  }
}

// ---------------- Wo GEMM: 64x128 tile, 512 blocks (2/CU), 256 threads ----------------
__global__ __launch_bounds__(256, 3) void gemm_wo(const u16* __restrict__ Cx,
    const u16* __restrict__ Wob, const float* __restrict__ bo, float* __restrict__ out) {
  __shared__ u16 As[4096], Bs[8192];   // A 64x64, B 128x64 (swizzled)
  const int tid = threadIdx.x;
  const int wv = tid >> 6, lane = tid & 63, l15 = lane & 15, quad = lane >> 4;
  const int bm = blockIdx.y * 64, bn = blockIdx.x * 128;

  const u16* gA[2]; const u16* gB[4];
  int ldsA[2], ldsB[4];
#pragma unroll
  for (int c = 0; c < 2; ++c) {
    int slot = c * 256 + wv * 64 + lane;
    int r = slot >> 3, cb = (slot & 7) ^ (r & 7);
    gA[c] = Cx + (size_t)(bm + r) * DM + cb * 8;
    ldsA[c] = (c * 256 + wv * 64) * 16;
  }
#pragma unroll
  for (int c = 0; c < 4; ++c) {
    int slot = c * 256 + wv * 64 + lane;
    int r = slot >> 3, cb = (slot & 7) ^ (r & 7);
    gB[c] = Wob + (size_t)(bn + r) * DM + cb * 8;
    ldsB[c] = (c * 256 + wv * 64) * 16;
  }

  int offA[2], offB[8][2];
#pragma unroll
  for (int h = 0; h < 2; ++h) {
    int rowA = wv * 16 + l15;
    offA[h] = ((rowA << 3) + ((quad + h * 4) ^ (l15 & 7))) << 4;
#pragma unroll
    for (int j = 0; j < 8; ++j) {
      int rowB = j * 16 + l15;
      offB[j][h] = ((rowB << 3) + ((quad + h * 4) ^ (l15 & 7))) << 4;
    }
  }

  f32x4 acc[8] = {};
  for (int k0 = 0; k0 < DM; k0 += 64) {
#pragma unroll
    for (int c = 0; c < 2; ++c) GLD16(gA[c] + k0, (char*)As + ldsA[c]);
#pragma unroll
    for (int c = 0; c < 4; ++c) GLD16(gB[c] + k0, (char*)Bs + ldsB[c]);
    __syncthreads();
    frag8 af0 = *(const frag8*)((const char*)As + offA[0]);
    frag8 af1 = *(const frag8*)((const char*)As + offA[1]);
#pragma unroll
    for (int j = 0; j < 8; ++j) {
      frag8 bf0 = *(const frag8*)((const char*)Bs + offB[j][0]);
      frag8 bf1 = *(const frag8*)((const char*)Bs + offB[j][1]);
      acc[j] = MFMA16(af0, bf0, acc[j]);
      acc[j] = MFMA16(af1, bf1, acc[j]);
    }
    __syncthreads();
  }

#pragma unroll
  for (int j = 0; j < 8; ++j) {
    int col = bn + j * 16 + l15;
    float bb = bo[col];
    int row0 = bm + wv * 16 + quad * 4;
#pragma unroll
    for (int r = 0; r < 4; ++r)
      out[(size_t)(row0 + r) * DM + col] = acc[j][r] + bb;
  }
}

// ---------------- Flash attention: 128-q blocks, LDS-staged, chained MFMA ----------------
// Units per bh: 8 heavy-split (strips 0..1 of 128 q x 4 segs of 8 tiles) +
// 14 light (128-q strips, q0 = 256+128i, tile-skip loop). Grid 22*32 = 704
// blocks — fully co-resident at 3/CU. Each wave: two 16-q groups (q, q+64)
// share the staged K/V tile; K-frags loaded once, V-frags feed both groups.
__global__ __launch_bounds__(256, 3) void attn_kernel(const u16* __restrict__ Q,
                                                      const u16* __restrict__ K,
                                                      const u16* __restrict__ Vt,
                                                      u16* __restrict__ Ctx,
                                                      float* __restrict__ Op,
                                                      float* __restrict__ Lp) {
  __shared__ u16 Ks[2][4096];     // [buf][64 keys x 64 d] swizzled
  __shared__ u16 Vs[2][4096];     // [buf][64 d x 64 keys] swizzled

  const int tid = threadIdx.x, w = tid >> 6, lane = tid & 63, l15 = lane & 15, quad = lane >> 4;
  const int blk = blockIdx.x;
  const int bh = blk & 31, unit = blk >> 5;
  const int b = bh >> 4, h = bh & 15;
  const bool heavy = unit < 8;
  const int strip = heavy ? (unit >> 2) : 0;
  const int q0 = heavy ? strip * 128 : 256 + (unit - 8) * 128;
  const int qw = q0 + w * 16;      // group g covers qw + g*64 .. +15

  // Q B-frags per group (n = q = l15, k = d = quad*8+j); Q carries SCL2
  frag8 bq[2][2];
#pragma unroll
  for (int g = 0; g < 2; ++g) {
    const u16* qrow = Q + (size_t)(b * S_ + qw + g * 64 + l15) * DM + h * 64;
    bq[g][0] = *(const frag8*)(qrow + quad * 8);
    bq[g][1] = *(const frag8*)(qrow + quad * 8 + 32);
  }

  // staging pointers; swizzle f(r) = (r&7) ^ (((r>>3)&1)<<2)
  const u16* gK[2]; const u16* gV[2]; int ldso[2];
#pragma unroll
  for (int c = 0; c < 2; ++c) {
    int sl = (w * 2 + c) * 64 + lane;
    int r = sl >> 3;
    int fr = (r & 7) ^ (((r >> 3) & 1) << 2);
    int cb = (sl & 7) ^ fr;
    gK[c] = K  + (size_t)(b * S_ + r) * DM + h * 64 + cb * 8;        // + kt*64*DM
    gV[c] = Vt + (size_t)(h * 64 + r) * BS_ + (size_t)b * S_ + cb * 8;  // + kt*64
    ldso[c] = (w * 2 + c) * 1024;
  }

  const int fl = (l15 & 7) ^ (((l15 >> 3) & 1) << 2);   // f(row) for row%16 = l15
  int offKb[2];
#pragma unroll
  for (int hh = 0; hh < 2; ++hh)
    offKb[hh] = ((l15 << 3) + ((quad + hh * 4) ^ fl)) << 4;
  int offVb[4];
#pragma unroll
  for (int kg = 0; kg < 4; ++kg)
    offVb[kg] = ((((l15 << 3) + ((((kg << 1) | (quad >> 1))) ^ fl)) << 4)
                 | ((quad & 1) << 3));

  int qidx[2]; bool qglob[2];
#pragma unroll
  for (int g = 0; g < 2; ++g) { qidx[g] = qw + g * 64 + l15; qglob[g] = qidx[g] < NG; }
  const frag4 ones = {(short)0x3F80, (short)0x3F80, (short)0x3F80, (short)0x3F80};

  f32x4 o[2][4] = {};     // O^T per group: row d = nt*16+quad*4+r, col q = l15
  f32x4 o_l[2] = {};      // lsum per group via ones-MFMA

  auto stage = [&](int t, int buf) {
#pragma unroll
    for (int c = 0; c < 2; ++c) {
      GLD16(gK[c] + (size_t)t * 64 * DM, (char*)Ks[buf] + ldso[c]);
      GLD16(gV[c] + t * 64,              (char*)Vs[buf] + ldso[c]);
    }
  };

  auto step = [&](int kt, int p, bool domask) {
    const char* kb_ = (const char*)Ks[p];
    const char* vb_ = (const char*)Vs[p];
    // K A-frags loaded once, used by both q-groups
    frag8 ak[4][2];
#pragma unroll
    for (int kg = 0; kg < 4; ++kg) {
      ak[kg][0] = *(const frag8*)(kb_ + offKb[0] + kg * 2048);
      ak[kg][1] = *(const frag8*)(kb_ + offKb[1] + kg * 2048);
    }
    const int k0 = kt * 64;
    frag4 pk[2][4];
#pragma unroll
    for (int g = 0; g < 2; ++g) {
      f32x4 st[4] = {};
#pragma unroll
      for (int kg = 0; kg < 4; ++kg) {
        st[kg] = MFMA16(ak[kg][0], bq[g][0], st[kg]);
        st[kg] = MFMA16(ak[kg][1], bq[g][1], st[kg]);
      }
      if (domask) {
#pragma unroll
        for (int kg = 0; kg < 4; ++kg) {
          float pr[4];
#pragma unroll
          for (int r = 0; r < 4; ++r) {
            int kc = k0 + kg * 16 + quad * 4 + r;
            int d = qidx[g] - kc;
            bool act = ((unsigned)(d + 64) <= 128u) || qglob[g] || (kc < NG);
            pr[r] = EXP2(act ? st[kg][r] : NEGF);
          }
          pk[g][kg] = frag4{(short)f2bfc(pr[0]), (short)f2bfc(pr[1]),
                            (short)f2bfc(pr[2]), (short)f2bfc(pr[3])};
        }
      } else {
#pragma unroll
        for (int kg = 0; kg < 4; ++kg) {
          float pr[4];
#pragma unroll
          for (int r = 0; r < 4; ++r) pr[r] = EXP2(st[kg][r]);
          pk[g][kg] = frag4{(short)f2bfc(pr[0]), (short)f2bfc(pr[1]),
                            (short)f2bfc(pr[2]), (short)f2bfc(pr[3])};
        }
      }
    }
    // PV: V^T frags read once, feed both groups
#pragma unroll
    for (int kg = 0; kg < 4; ++kg) {
      o_l[0] = mfma_16x16x16_bf16(ones, pk[0][kg], o_l[0]);
      o_l[1] = mfma_16x16x16_bf16(ones, pk[1][kg], o_l[1]);
#pragma unroll
      for (int nt = 0; nt < 4; ++nt) {
        frag4 av = *(const frag4*)(vb_ + offVb[kg] + nt * 2048);
        o[0][nt] = mfma_16x16x16_bf16(av, pk[0][kg], o[0][nt]);
        o[1][nt] = mfma_16x16x16_bf16(av, pk[1][kg], o[1][nt]);
      }
    }
  };

  if (heavy) {
    const int seg = unit & 3;
    const int kt0 = seg * 8;
    const bool dm = (strip == 1);         // q 128..255 straddles NG cutoff
    int p = 0;
    stage(kt0, 0);
#pragma unroll 1
    for (int tt = 0; tt < 8; ++tt) {
      __syncthreads();
      if (tt < 7) stage(kt0 + tt + 1, p ^ 1);
      step(kt0 + tt, p, dm && (kt0 + tt > 2));
      p ^= 1;
    }
    // partials: Op[(bh*2+strip)*4+seg][q 0..127][d 0..63], Lp[...][q 0..127]
    float* op = Op + ((size_t)((bh * 2 + strip) * 4 + seg)) * 8192;
    float* lp = Lp + ((size_t)((bh * 2 + strip) * 4 + seg)) * 128;
#pragma unroll
    for (int g = 0; g < 2; ++g) {
      int rl = g * 64 + w * 16 + l15;
      if (quad == 0) lp[rl] = o_l[g][0];
#pragma unroll
      for (int nt = 0; nt < 4; ++nt)
        *(float4*)&op[rl * 64 + nt * 16 + quad * 4] =
            make_float4(o[g][nt][0], o[g][nt][1], o[g][nt][2], o[g][nt][3]);
    }
    return;
  }

  // light path: q0 >= 256, tile-skip loop (global cols 0..3 + window band)
  auto activef = [&](int t) {
    int k0 = t * 64;
    return (k0 < NG) || (k0 + 63 >= q0 - 64 && k0 <= q0 + 127 + 64);
  };
  auto nextt = [&](int cur) { int n = cur + 1; while (n < 32 && !activef(n)) ++n; return n; };

  int kt = 0, p = 0;                      // tile 0 always active (global cols)
  stage(0, 0);
  for (;;) {
    int ktn = nextt(kt);
    bool more = ktn < 32;
    __syncthreads();
    if (more) stage(ktn, p ^ 1);
    step(kt, p, kt > 2);
    if (!more) break;
    kt = ktn; p ^= 1;
  }

#pragma unroll
  for (int g = 0; g < 2; ++g) {
    float inv = 1.0f / o_l[g][0];
    u16* crow = Ctx + (size_t)((size_t)b * S_ + qw + g * 64 + l15) * DM + h * 64;
#pragma unroll
    for (int nt = 0; nt < 4; ++nt) {
      u32 lo = (u32)f2bf(o[g][nt][0] * inv) | ((u32)f2bf(o[g][nt][1] * inv) << 16);
      u32 hi = (u32)f2bf(o[g][nt][2] * inv) | ((u32)f2bf(o[g][nt][3] * inv) << 16);
      *(uint2*)&crow[nt * 16 + quad * 4] = make_uint2(lo, hi);
    }
  }
}

// ---------------- combine split-K partials -> Ctx rows 0..255 ----------------
// 128 blocks (4 strips of 64 q x 32 bh), 256 thr: row = t>>2, 16 d-cols each.
__global__ __launch_bounds__(256) void combine_kernel(const float* __restrict__ Op,
                                                      const float* __restrict__ Lp,
                                                      u16* __restrict__ Ctx) {
  const int blk = blockIdx.x;
  const int bh = blk & 31, s64 = blk >> 5;      // 64-row strip 0..3
  const int b = bh >> 4, h = bh & 15;
  const int t = threadIdx.x;
  const int row = t >> 2, colg = (t & 3) * 16;
  const int gq = s64 * 64 + row;                 // 0..255
  const int strip = gq >> 7, rIn = gq & 127;     // 128-row partial index

  const float* opb = Op + ((size_t)(bh * 2 + strip) * 4) * 8192;
  const float* lpb = Lp + ((size_t)(bh * 2 + strip) * 4) * 128;

  float l = lpb[rIn] + lpb[128 + rIn] + lpb[256 + rIn] + lpb[384 + rIn];
  float acc[16];
#pragma unroll
  for (int e = 0; e < 16; ++e) acc[e] = opb[rIn * 64 + colg + e];
#pragma unroll
  for (int seg = 1; seg < 4; ++seg)
#pragma unroll
    for (int e = 0; e < 16; ++e) acc[e] += opb[seg * 8192 + rIn * 64 + colg + e];

  float inv = 1.0f / l;
  u32 pk[8];
#pragma unroll
  for (int p = 0; p < 8; ++p)
    pk[p] = (u32)f2bf(acc[2 * p] * inv) | ((u32)f2bf(acc[2 * p + 1] * inv) << 16);
  u16* dst = Ctx + (size_t)((size_t)b * S_ + gq) * DM + h * 64 + colg;
  *(uint4*)dst       = make_uint4(pk[0], pk[1], pk[2], pk[3]);
  *(uint4*)(dst + 8) = make_uint4(pk[4], pk[5], pk[6], pk[7]);
}

// ---------------- launch ----------------
extern "C" void kernel_launch(void* const* d_in, const int* in_sizes, int n_in,
                              void* d_out, int out_size, void* d_ws, size_t ws_size,
                              hipStream_t stream) {
  const float* X  = (const float*)d_in[0];
  const float* Wq = (const float*)d_in[1];
  const float* bq = (const float*)d_in[2];
  const float* Wk = (const float*)d_in[3];
  const float* bk = (const float*)d_in[4];
  const float* Wv = (const float*)d_in[5];
  const float* bv = (const float*)d_in[6];
  const float* Wo = (const float*)d_in[7];
  const float* bo = (const float*)d_in[8];
  float* out = (float*)d_out;

  u16* ws = (u16*)d_ws;
  const size_t NX = (size_t)BS_ * DM;
  const size_t NW = (size_t)DM * DM;
  u16* Xb  = ws;
  u16* Wqb = Xb + NX;
  u16* Wkb = Wqb + NW;
  u16* Wvb = Wkb + NW;
  u16* Wob = Wvb + NW;
  u16* Qb  = Wob + NW;
  u16* Kb  = Qb + NX;
  u16* Vt  = Kb + NX;
  u16* Cx  = Vt + NX;
  float* Op = (float*)(Cx + NX);               // 32*2*4*8192 = 2.1M floats (8 MB)
  float* Lp = Op + (size_t)32 * 2 * 4 * 8192;  // 32k floats

  cvt_all<<<dim3(1024, 8), 256, 0, stream>>>(X, Wq, Wk, Wv, Wo, Xb, Wqb, Wkb, Wvb, Wob);
  gemm_qkv<<<dim3(24, 32), 256, 0, stream>>>(Xb, Wqb, Wkb, Wvb, bq, bk, bv, Qb, Kb, Vt);
  attn_kernel<<<22 * 32, 256, 0, stream>>>(Qb, Kb, Vt, Cx, Op, Lp);
  combine_kernel<<<128, 256, 0, stream>>>(Op, Lp, Cx);
  gemm_wo<<<dim3(8, 64), 256, 0, stream>>>(Cx, Wob, bo, out);
}